// Round 8
// baseline (545.088 us; speedup 1.0000x reference)
//
#include <hip/hip_runtime.h>
#include <stdint.h>

// ISTA_Net fused MFMA implementation for gfx950.  Round 16:
// R15 base (354.5us steady, conflicts 3.37e7->1.03e6 via +8B row padding) +
// two independent stall reductions:
// 1) Branch-free shrink epilogue: rs=max(|v|-eta,0); ls+=rs; s=copysign(rs,v)
//    (divergent cndmask chains -> 6 straight-line ops; arithmetic identical).
// 2) Full-width zf8 [32][1024] fp8 (stride 1032B = 8 mod 128, 2-way clean)
//    aliasing ALL of buf0 (x dead after gx epilogue).  All 4 B-passes run
//    back-to-back, Phase C merges into ONE 32-dkc ring loop (A-blocks are
//    contiguous: w*32+dkc).  Barriers 6->4/iter, one C cold-start not two.
//    xm accumulation order unchanged (c=0 then c=1) -> bit-identical.
// Shapes: M=1024, N=128, K=256, T=10, BATCH=8192. LAMBD=1.
// Outputs: x_T(2,8192,256) ++ loss_sparse ++ loss_eq/T ++ out_sparse

typedef short s8v __attribute__((ext_vector_type(8)));   // 8 bf16 MFMA operand
typedef short s4v __attribute__((ext_vector_type(4)));
typedef float f16v __attribute__((ext_vector_type(16))); // 32x32 MFMA accumulator
typedef long long i64;

#define MFMA(a, b, c)  __builtin_amdgcn_mfma_f32_32x32x16_bf16((a), (b), (c), 0, 0, 0)
#define MFMA8(a, b, c) __builtin_amdgcn_mfma_f32_32x32x16_fp8_fp8((a), (b), (c), 0, 0, 0)

__device__ __forceinline__ short f2bf(float f) {
  uint32_t u = __builtin_bit_cast(uint32_t, f);
  u = (u + 0x7FFFu + ((u >> 16) & 1u)) >> 16;   // RNE
  return (short)u;
}
__device__ __forceinline__ float bf2f(short s) {
  uint32_t u = ((uint32_t)(uint16_t)s) << 16;
  return __builtin_bit_cast(float, u);
}
__device__ __forceinline__ unsigned char f2fp8(float v) {
  return (unsigned char)(__builtin_amdgcn_cvt_pk_fp8_f32(v, 0.f, 0, false) & 0xFF);
}
__device__ __forceinline__ int pk4fp8(float a, float b, float c, float d) {
  int r = __builtin_amdgcn_cvt_pk_fp8_f32(a, b, 0, false);
  r = __builtin_amdgcn_cvt_pk_fp8_f32(c, d, r, true);
  return r;
}

// async 16B/lane global->LDS DMA (per-lane gptr; wave-uniform LDS base,
// HW scatters lane i -> base + 16*i)
__device__ __forceinline__ void glds16(const void* g, void* l) {
  __builtin_amdgcn_global_load_lds(
      (const __attribute__((address_space(1))) void*)g,
      (__attribute__((address_space(3))) void*)l, 16, 0, 0);
}
__device__ __forceinline__ void waitvm(int n) {
  if (n <= 0)      asm volatile("s_waitcnt vmcnt(0)" ::: "memory");
  else if (n == 2) asm volatile("s_waitcnt vmcnt(2)" ::: "memory");
  else             asm volatile("s_waitcnt vmcnt(4)" ::: "memory");
}

// ---------------- merged prep kernel ----------------
// bf16 packed layout (Cbp/WXbp): idx = ((tile*KC + kc)*2 + h)*256 + l31*8 + j
// fp8 DMA-block layout (E0f8p/E0Tf8p): per (tile, dkc, sec) 1KB block;
//   byte u*8+jj, u = t*64 + h*32 + l31 -> element (k = (2dkc+t)*16 + h*8 + jj)
// Block ranges: [0,768) Cbp | [768,1024) WXbp | [1024,3072) E0f8p |
//               [3072,5120) E0Tf8p | 5120 zero-tail

__global__ void prep_all(const float* __restrict__ W, const float* __restrict__ WX,
                         const float* __restrict__ E0,
                         short* __restrict__ Cbp, short* __restrict__ WXbp,
                         unsigned char* __restrict__ E0f8p,
                         unsigned char* __restrict__ E0Tf8p,
                         float* __restrict__ out) {
  const int b = blockIdx.x;
  if (b < 768) {
    // Cbp: sections [C0, C1, -C1] (65536 shorts each), C = WX*W (256x256), KC=16
    const int idx = b * 256 + threadIdx.x;
    const int sec = idx >> 16, r = idx & 65535;
    const int j = r & 7, l31 = (r >> 3) & 31, h = (r >> 8) & 1, kc = (r >> 9) & 15, rt = r >> 13;
    const int i = rt * 32 + l31, col = kc * 16 + h * 8 + j;
    float c0 = 0.f, c1 = 0.f;
    for (int n = 0; n < 128; n++) {
      const float wx0 = WX[i * 128 + n], wx1 = WX[32768 + i * 128 + n];
      const float w0 = W[n * 256 + col], w1 = W[32768 + n * 256 + col];
      c0 += wx0 * w0 - wx1 * w1;
      c1 += wx0 * w1 + wx1 * w0;
    }
    Cbp[idx] = f2bf(sec == 0 ? c0 : (sec == 1 ? c1 : -c1));
  } else if (b < 1024) {
    // WXbp: sections [-WX0, -WX1] (32768 shorts each), rows k(256), cols n(128), KC=8
    const int idx = (b - 768) * 256 + threadIdx.x;
    const int sec = idx >> 15, r = idx & 32767;
    const int j = r & 7, l31 = (r >> 3) & 31, h = (r >> 8) & 1, kc = (r >> 9) & 7, rt = r >> 12;
    const int row = rt * 32 + l31, col = kc * 16 + h * 8 + j;
    WXbp[idx] = f2bf(-WX[sec * 32768 + row * 128 + col]);
  } else if (b < 3072) {
    // E0f8p: sections [16*E0_re, -16*E0_im], rows m(1024), cols k(256); 8 dkc/m-tile
    const int idx = (b - 1024) * 256 + threadIdx.x;   // [0, 524288)
    const int sec = idx >> 18, r = idx & 262143;
    const int blk = r >> 10, within = r & 1023;
    const int mt = blk >> 3, dkc = blk & 7;
    const int u = within >> 3, jj = within & 7;
    const int t = u >> 6, h = (u >> 5) & 1, l31 = u & 31;
    const int m = mt * 32 + l31, k = (dkc * 2 + t) * 16 + h * 8 + jj;
    const float v = E0[sec * 262144 + m * 256 + k] * (sec ? -16.f : 16.f);
    E0f8p[idx] = f2fp8(v);
  } else if (b < 5120) {
    // E0Tf8p: sections [16*E0_re^T, -16*E0_im^T], rows k(256), cols m(1024);
    // blocks (rt, c, dkc16)
    const int idx = (b - 3072) * 256 + threadIdx.x;   // [0, 524288)
    const int sec = idx >> 18, r = idx & 262143;
    const int blk = r >> 10, within = r & 1023;
    const int rt = blk >> 5, rem = blk & 31;
    const int c = rem >> 4, dkc = rem & 15;
    const int u = within >> 3, jj = within & 7;
    const int t = u >> 6, h = (u >> 5) & 1, l31 = u & 31;
    const int krow = rt * 32 + l31;
    const int mcol = c * 512 + (dkc * 2 + t) * 16 + h * 8 + jj;
    const float v = E0[sec * 262144 + mcol * 256 + krow] * (sec ? -16.f : 16.f);
    E0Tf8p[idx] = f2fp8(v);
  } else {
    if (threadIdx.x < 3) out[4194304 + threadIdx.x] = 0.f;
  }
}

// ---------------- main fused kernel ----------------
// grid 256 (batch tile of 32), block 512 (8 waves; wave w = row-tile).
// LDS (padded rows; all strides % 128B in {8,16->only 8 used} -> <=2-way):
//   buf0 [2][32][260]s = 33280B : x bf16; ENTIRE buf aliased during B/C as
//                                 zf8 [32][1032B] fp8 (full 1024 m cols)
//   buf1 [2][32][260]s = 33280B : gx bf16 (true scale, Phase D huber)
//   bufy [3][32][132]s = 25344B : y bf16 [y0|y1|-y1]
//   gxf8 [2][32][264B] = 16896B : gx/S fp8 (Phase B B-operand)
//   ring0..2 (3 x 16KB)         : per-wave DMA slots (2KB/wave)
// Total ~154.25KB -> 1 block/CU.

#define RING(s) (((s) % 3) == 0 ? ring0 : ((s) % 3) == 1 ? ring1 : ring2)

__global__ __attribute__((amdgpu_flat_work_group_size(512, 512), amdgpu_waves_per_eu(2, 2)))
void ista_main(
    const float* __restrict__ y,
    const float* __restrict__ etas,
    const float* __restrict__ gammas,
    const short* __restrict__ Cbp,
    const short* __restrict__ WXbp,
    const unsigned char* __restrict__ E0f8p,
    const unsigned char* __restrict__ E0Tf8p,
    float* __restrict__ out) {
  __shared__ short buf0[16640];
  __shared__ short buf1[16640];
  __shared__ short bufy[12672];
  __shared__ unsigned char gxf8[16896];
  __shared__ unsigned char ring0[16384];
  __shared__ unsigned char ring1[16384];
  __shared__ unsigned char ring2[16384];
  unsigned char* zf8 = (unsigned char*)buf0;   // [32][1032B] fp8, aliases ALL x

  const int tid = threadIdx.x;
  const int w = tid >> 6;          // wave 0..7 == row-tile
  const int lane = tid & 63;
  const int l31 = lane & 31;
  const int h = lane >> 5;         // half-wave
  const int b0 = blockIdx.x * 32;
  const int lq = l31 * 8;          // bf16 packed-fragment lane offset (shorts)
  const int lane16 = lane * 16;    // per-lane global DMA offset (bytes)
  const int wslot = w * 2048;      // per-wave ring slot base (bytes)

  // ---- stage y -> bufy: [0]=y_re, [1]=y_im, [2]=-y_im  (rows 132 shorts)
  {
    const int bt = tid >> 4, j = tid & 15;
    const float* yb = y + (size_t)(b0 + bt) * 256;
    #pragma unroll
    for (int rep = 0; rep < 2; rep++) {
      const int jj = j + rep * 16;
      const int ch = jj >> 4, n8 = (jj & 15) << 3;
      const float4 v0 = *(const float4*)(yb + ch * 128 + n8);
      const float4 v1 = *(const float4*)(yb + ch * 128 + n8 + 4);
      s8v pk;
      pk[0] = f2bf(v0.x); pk[1] = f2bf(v0.y); pk[2] = f2bf(v0.z); pk[3] = f2bf(v0.w);
      pk[4] = f2bf(v1.x); pk[5] = f2bf(v1.y); pk[6] = f2bf(v1.z); pk[7] = f2bf(v1.w);
      const int off = bt * 132 + n8;
      *(s8v*)(bufy + ch * 4224 + off) = pk;
      if (ch == 1) {
        s8v nk;
        #pragma unroll
        for (int e = 0; e < 8; e++) nk[e] = pk[e] ^ (short)0x8000;
        *(s8v*)(bufy + 8448 + off) = nk;
      }
    }
  }
  // ---- zero buf0 (x = 0), including pad columns
  {
    s8v z = {0, 0, 0, 0, 0, 0, 0, 0};
    for (int i = tid * 8; i < 16640; i += 4096) *(s8v*)(buf0 + i) = z;
  }
  __syncthreads();

  float ls = 0.f, leq = 0.f, cntf = 0.f;
  float S = 1.f;                   // dynamic scale: gx/S, s/S stored fp8
  float s16_last = 0.0625f;
  f16v xm0, xm1;
  #pragma unroll
  for (int r = 0; r < 16; r++) { xm0[r] = 0.f; xm1[r] = 0.f; }

  #pragma unroll 1
  for (int it = 1; it <= 10; it++) {
    const float gam = gammas[it];
    const float eta = etas[it];
    const float invS = 1.f / S;
    const float s16 = S * 0.0625f;   // accumulator -> true scale (weights x16)
    s16_last = s16;

    // ======== Phase A (bf16): ac = C*x - d~ ; gx = x - gam*ac ========
    f16v ac0, ac1;
    #pragma unroll
    for (int r = 0; r < 16; r++) { ac0[r] = 0.f; ac1[r] = 0.f; }
    #pragma unroll
    for (int kc = 0; kc < 8; kc++) {       // -d~ = (-WX) * y
      const int pa = ((w * 8 + kc) * 2 + h) * 256 + lq;
      const s8v a0 = *(const s8v*)(WXbp + pa);
      const s8v a1 = *(const s8v*)(WXbp + 32768 + pa);
      const int yo = l31 * 132 + ((kc * 2 + h) << 3);
      const s8v by0 = *(const s8v*)(bufy + yo);
      const s8v by1 = *(const s8v*)(bufy + 4224 + yo);
      const s8v by1n = *(const s8v*)(bufy + 8448 + yo);
      ac0 = MFMA(a0, by0, ac0);
      ac0 = MFMA(a1, by1n, ac0);
      ac1 = MFMA(a0, by1, ac1);
      ac1 = MFMA(a1, by0, ac1);
    }
    if (it > 1) {
      #pragma unroll
      for (int kc = 0; kc < 16; kc++) {    // + C * x   (x = 0 at it=1)
        const int pa = ((w * 16 + kc) * 2 + h) * 256 + lq;
        const s8v a0 = *(const s8v*)(Cbp + pa);
        const s8v a1 = *(const s8v*)(Cbp + 65536 + pa);
        const s8v a1n = *(const s8v*)(Cbp + 131072 + pa);
        const int xo = l31 * 260 + ((kc * 2 + h) << 3);
        const s8v bx0 = *(const s8v*)(buf0 + xo);
        const s8v bx1 = *(const s8v*)(buf0 + 8320 + xo);
        ac0 = MFMA(a0, bx0, ac0);
        ac0 = MFMA(a1n, bx1, ac0);
        ac1 = MFMA(a0, bx1, ac1);
        ac1 = MFMA(a1, bx0, ac1);
      }
    }
    // gx = x - gam*ac; write gx bf16 (true) -> buf1, gx*invS fp8 -> gxf8
    #pragma unroll
    for (int r1 = 0; r1 < 4; r1++) {
      const int k0 = w * 32 + 8 * r1 + 4 * h;
      const int idx = l31 * 260 + k0;
      const s4v xv0 = *(const s4v*)(buf0 + idx);
      const s4v xv1 = *(const s4v*)(buf0 + 8320 + idx);
      float g0[4], g1[4];
      s4v p0, p1;
      #pragma unroll
      for (int r0 = 0; r0 < 4; r0++) {
        g0[r0] = bf2f(xv0[r0]) - gam * ac0[r1 * 4 + r0];
        g1[r0] = bf2f(xv1[r0]) - gam * ac1[r1 * 4 + r0];
        p0[r0] = f2bf(g0[r0]);
        p1[r0] = f2bf(g1[r0]);
      }
      *(s4v*)(buf1 + idx) = p0;
      *(s4v*)(buf1 + 8320 + idx) = p1;
      const int ga = l31 * 264 + k0;
      *(int*)(gxf8 + ga) = pk4fp8(g0[0] * invS, g0[1] * invS, g0[2] * invS, g0[3] * invS);
      *(int*)(gxf8 + 8448 + ga) = pk4fp8(g1[0] * invS, g1[1] * invS, g1[2] * invS, g1[3] * invS);
    }
    __syncthreads();

    #pragma unroll
    for (int r = 0; r < 16; r++) { xm0[r] = 0.f; xm1[r] = 0.f; }

    // ---- Phase B (fp8): z = Re(E0 * gx); 4 passes (c,q), 3-slot DMA ring.
    // All passes write full-width zf8 [32][1032B]; no barriers in between
    // (zf8 columns are wave-disjoint: col = c*512 + (q*8+w)*32 + ...).
    #pragma unroll 1
    for (int p = 0; p < 4; p++) {
      const int c = p >> 1, q = p & 1;
      const int mt = c * 16 + q * 8 + w;
      const unsigned char* gb = E0f8p + (size_t)(mt * 8) * 1024 + lane16;
      f16v zq;
      #pragma unroll
      for (int r = 0; r < 16; r++) zq[r] = 0.f;

#define B_ISSUE(d) do { \
    unsigned char* _s = RING(d) + wslot; \
    glds16(gb + (d) * 1024, _s); \
    glds16(gb + 262144 + (d) * 1024, _s + 1024); \
  } while (0)

      B_ISSUE(0); B_ISSUE(1); B_ISSUE(2);
      #pragma unroll
      for (int dkc = 0; dkc < 8; dkc++) {
        waitvm(2 * (7 - dkc < 2 ? 7 - dkc : 2));
        const unsigned char* Sl = RING(dkc) + wslot;
        __builtin_amdgcn_s_setprio(1);
        #pragma unroll
        for (int t = 0; t < 2; t++) {
          const i64 are = *(const i64*)(Sl + t * 512 + h * 256 + l31 * 8);
          const i64 aim = *(const i64*)(Sl + 1024 + t * 512 + h * 256 + l31 * 8);
          const int kc = dkc * 2 + t;
          const int go = l31 * 264 + (kc << 4) + h * 8;
          const i64 bg0 = *(const i64*)(gxf8 + go);
          const i64 bg1 = *(const i64*)(gxf8 + 8448 + go);
          zq = MFMA8(are, bg0, zq);
          zq = MFMA8(aim, bg1, zq);
        }
        __builtin_amdgcn_s_setprio(0);
        if (dkc + 3 < 8) B_ISSUE(dkc + 3);
      }
#undef B_ISSUE

      // shrink + losses (branch-free); write s*invS fp8 -> zf8 [32][1032B]
      #pragma unroll
      for (int r1 = 0; r1 < 4; r1++) {
        float sv[4];
        #pragma unroll
        for (int r0 = 0; r0 < 4; r0++) {
          const float v = zq[r1 * 4 + r0] * s16;   // true z
          const float av = fabsf(v) - eta;
          const float rs = fmaxf(av, 0.f);
          ls += rs;
          if (it == 10) cntf += (rs > 1e-3f) ? 1.f : 0.f;
          sv[r0] = copysignf(rs, v) * invS;
        }
        const int mcol = c * 512 + (q * 8 + w) * 32 + 8 * r1 + 4 * h;
        const int za = l31 * 1032 + mcol;
        *(int*)(zf8 + za) = pk4fp8(sv[0], sv[1], sv[2], sv[3]);
      }
    }
    __syncthreads();

    // ---- Phase C (fp8): xm += [E0reT; -E0imT] * s over ALL 1024 m cols;
    // single 32-dkc ring loop (A-blocks contiguous at w*32 + dkc).
    {
      const unsigned char* tb = E0Tf8p + (size_t)(w * 32) * 1024 + lane16;
#define C_ISSUE(d) do { \
    unsigned char* _s = RING(d) + wslot; \
    glds16(tb + (d) * 1024, _s); \
    glds16(tb + 262144 + (d) * 1024, _s + 1024); \
  } while (0)

      C_ISSUE(0); C_ISSUE(1); C_ISSUE(2);
      #pragma unroll
      for (int dkc = 0; dkc < 32; dkc++) {
        waitvm(2 * (31 - dkc < 2 ? 31 - dkc : 2));
        const unsigned char* Sl = RING(dkc) + wslot;
        __builtin_amdgcn_s_setprio(1);
        #pragma unroll
        for (int t = 0; t < 2; t++) {
          const i64 a0 = *(const i64*)(Sl + t * 512 + h * 256 + l31 * 8);
          const i64 a1 = *(const i64*)(Sl + 1024 + t * 512 + h * 256 + l31 * 8);
          const int kc = dkc * 2 + t;
          const i64 bz = *(const i64*)(zf8 + l31 * 1032 + (kc << 4) + h * 8);
          xm0 = MFMA8(a0, bz, xm0);
          xm1 = MFMA8(a1, bz, xm1);
        }
        __builtin_amdgcn_s_setprio(0);
        if (dkc + 3 < 32) C_ISSUE(dkc + 3);
      }
#undef C_ISSUE
    }
    __syncthreads();

    // ======== Phase D: huber(gx, xm*s16); x = xm*s16 (bf16) -> buf0 ========
    #pragma unroll
    for (int r1 = 0; r1 < 4; r1++) {
      const int k0 = w * 32 + 8 * r1 + 4 * h;
      const int idx = l31 * 260 + k0;
      const s4v gv0 = *(const s4v*)(buf1 + idx);
      const s4v gv1 = *(const s4v*)(buf1 + 8320 + idx);
      s4v p0, p1;
      #pragma unroll
      for (int r0 = 0; r0 < 4; r0++) {
        const float x0 = xm0[r1 * 4 + r0] * s16, x1 = xm1[r1 * 4 + r0] * s16;
        const float d0 = bf2f(gv0[r0]) - x0;
        const float d1 = bf2f(gv1[r0]) - x1;
        const float a0 = fabsf(d0), a1 = fabsf(d1);
        leq += (a0 < 1.f) ? 0.5f * d0 * d0 : (a0 - 0.5f);
        leq += (a1 < 1.f) ? 0.5f * d1 * d1 : (a1 - 0.5f);
        p0[r0] = f2bf(x0);
        p1[r0] = f2bf(x1);
      }
      *(s4v*)(buf0 + idx) = p0;
      *(s4v*)(buf0 + 8320 + idx) = p1;
    }
    __syncthreads();
    S *= 8.f;   // x grows ~9.3x/iter; keep fp8-stored gx/s near O(1)
  }

  // ---- write x_T (2, 8192, 256) fp32 from final xm (true scale)
  {
    const size_t ob = (size_t)(b0 + l31) * 256;
    #pragma unroll
    for (int r1 = 0; r1 < 4; r1++) {
      const int k0 = w * 32 + 8 * r1 + 4 * h;
      float4 v0, v1;
      v0.x = xm0[r1 * 4 + 0] * s16_last; v0.y = xm0[r1 * 4 + 1] * s16_last;
      v0.z = xm0[r1 * 4 + 2] * s16_last; v0.w = xm0[r1 * 4 + 3] * s16_last;
      v1.x = xm1[r1 * 4 + 0] * s16_last; v1.y = xm1[r1 * 4 + 1] * s16_last;
      v1.z = xm1[r1 * 4 + 2] * s16_last; v1.w = xm1[r1 * 4 + 3] * s16_last;
      *(float4*)(out + ob + k0) = v0;
      *(float4*)(out + 2097152 + ob + k0) = v1;
    }
  }
  // ---- scalar reductions
  #pragma unroll
  for (int off = 32; off > 0; off >>= 1) {
    ls += __shfl_down(ls, off);
    leq += __shfl_down(leq, off);
    cntf += __shfl_down(cntf, off);
  }
  if (lane == 0) {
    atomicAdd(out + 4194304, ls * (1.f / 8192.f));
    atomicAdd(out + 4194305, leq * (1.f / (2.f * 256.f * 8192.f * 10.f)));
    atomicAdd(out + 4194306, cntf * (1.f / 8192.f));
  }
}

extern "C" void kernel_launch(void* const* d_in, const int* in_sizes, int n_in,
                              void* d_out, int out_size, void* d_ws, size_t ws_size,
                              hipStream_t stream) {
  (void)in_sizes; (void)n_in; (void)out_size; (void)ws_size;
  const float* y = (const float*)d_in[0];
  const float* W = (const float*)d_in[1];
  const float* WX = (const float*)d_in[2];
  const float* E0 = (const float*)d_in[3];
  const float* etas = (const float*)d_in[4];
  const float* gammas = (const float*)d_in[5];
  float* out = (float*)d_out;

  short* Cbp = (short*)d_ws;                       // 3 * 65536 shorts
  short* WXbp = Cbp + 196608;                      // 2 * 32768 shorts
  unsigned char* E0f8p = (unsigned char*)(WXbp + 65536);   // 524288 B
  unsigned char* E0Tf8p = E0f8p + 524288;                  // 524288 B (~1.6 MB total)

  prep_all<<<5121, 256, 0, stream>>>(W, WX, E0, Cbp, WXbp, E0f8p, E0Tf8p, out);
  ista_main<<<256, 512, 0, stream>>>(y, etas, gammas, Cbp, WXbp, E0f8p, E0Tf8p, out);
}

// Round 9
// 393.767 us; speedup vs baseline: 1.3843x; 1.3843x over previous
//
#include <hip/hip_runtime.h>
#include <stdint.h>

// ISTA_Net fused MFMA implementation for gfx950.  Round 17:
// R15 structure EXACTLY (354.5us steady, 11MB FETCH, conflicts 1.03e6) +
// branch-free shrink epilogue ONLY.
// R16 post-mortem: merging B passes + single 32-dkc C loop (fewer barriers,
// 2x phase windows) broke the cross-CU L2 convoy on the weight stream:
// FETCH 11->304MB (L2-miss traffic), +140us.  BANNED: reducing barrier
// cadence / growing phase windows past ~256KB.  The branch-free shrink
// (rs=max(|v|-eta,0); ls+=rs; s=copysign(rs,v)) is pure VALU and is the one
// R16 piece worth keeping -- isolated here as a single variable vs R15.
// Shapes: M=1024, N=128, K=256, T=10, BATCH=8192. LAMBD=1.
// Outputs: x_T(2,8192,256) ++ loss_sparse ++ loss_eq/T ++ out_sparse

typedef short s8v __attribute__((ext_vector_type(8)));   // 8 bf16 MFMA operand
typedef short s4v __attribute__((ext_vector_type(4)));
typedef float f16v __attribute__((ext_vector_type(16))); // 32x32 MFMA accumulator
typedef long long i64;

#define MFMA(a, b, c)  __builtin_amdgcn_mfma_f32_32x32x16_bf16((a), (b), (c), 0, 0, 0)
#define MFMA8(a, b, c) __builtin_amdgcn_mfma_f32_32x32x16_fp8_fp8((a), (b), (c), 0, 0, 0)

__device__ __forceinline__ short f2bf(float f) {
  uint32_t u = __builtin_bit_cast(uint32_t, f);
  u = (u + 0x7FFFu + ((u >> 16) & 1u)) >> 16;   // RNE
  return (short)u;
}
__device__ __forceinline__ float bf2f(short s) {
  uint32_t u = ((uint32_t)(uint16_t)s) << 16;
  return __builtin_bit_cast(float, u);
}
__device__ __forceinline__ unsigned char f2fp8(float v) {
  return (unsigned char)(__builtin_amdgcn_cvt_pk_fp8_f32(v, 0.f, 0, false) & 0xFF);
}
__device__ __forceinline__ int pk4fp8(float a, float b, float c, float d) {
  int r = __builtin_amdgcn_cvt_pk_fp8_f32(a, b, 0, false);
  r = __builtin_amdgcn_cvt_pk_fp8_f32(c, d, r, true);
  return r;
}

// async 16B/lane global->LDS DMA (per-lane gptr; wave-uniform LDS base,
// HW scatters lane i -> base + 16*i)
__device__ __forceinline__ void glds16(const void* g, void* l) {
  __builtin_amdgcn_global_load_lds(
      (const __attribute__((address_space(1))) void*)g,
      (__attribute__((address_space(3))) void*)l, 16, 0, 0);
}
__device__ __forceinline__ void waitvm(int n) {
  if (n <= 0)      asm volatile("s_waitcnt vmcnt(0)" ::: "memory");
  else if (n == 2) asm volatile("s_waitcnt vmcnt(2)" ::: "memory");
  else             asm volatile("s_waitcnt vmcnt(4)" ::: "memory");
}

// ---------------- merged prep kernel ----------------
// bf16 packed layout (Cbp/WXbp): idx = ((tile*KC + kc)*2 + h)*256 + l31*8 + j
// fp8 DMA-block layout (E0f8p/E0Tf8p): per (tile, dkc, sec) 1KB block;
//   byte u*8+jj, u = t*64 + h*32 + l31 -> element (k = (2dkc+t)*16 + h*8 + jj)
// Block ranges: [0,768) Cbp | [768,1024) WXbp | [1024,3072) E0f8p |
//               [3072,5120) E0Tf8p | 5120 zero-tail

__global__ void prep_all(const float* __restrict__ W, const float* __restrict__ WX,
                         const float* __restrict__ E0,
                         short* __restrict__ Cbp, short* __restrict__ WXbp,
                         unsigned char* __restrict__ E0f8p,
                         unsigned char* __restrict__ E0Tf8p,
                         float* __restrict__ out) {
  const int b = blockIdx.x;
  if (b < 768) {
    // Cbp: sections [C0, C1, -C1] (65536 shorts each), C = WX*W (256x256), KC=16
    const int idx = b * 256 + threadIdx.x;
    const int sec = idx >> 16, r = idx & 65535;
    const int j = r & 7, l31 = (r >> 3) & 31, h = (r >> 8) & 1, kc = (r >> 9) & 15, rt = r >> 13;
    const int i = rt * 32 + l31, col = kc * 16 + h * 8 + j;
    float c0 = 0.f, c1 = 0.f;
    for (int n = 0; n < 128; n++) {
      const float wx0 = WX[i * 128 + n], wx1 = WX[32768 + i * 128 + n];
      const float w0 = W[n * 256 + col], w1 = W[32768 + n * 256 + col];
      c0 += wx0 * w0 - wx1 * w1;
      c1 += wx0 * w1 + wx1 * w0;
    }
    Cbp[idx] = f2bf(sec == 0 ? c0 : (sec == 1 ? c1 : -c1));
  } else if (b < 1024) {
    // WXbp: sections [-WX0, -WX1] (32768 shorts each), rows k(256), cols n(128), KC=8
    const int idx = (b - 768) * 256 + threadIdx.x;
    const int sec = idx >> 15, r = idx & 32767;
    const int j = r & 7, l31 = (r >> 3) & 31, h = (r >> 8) & 1, kc = (r >> 9) & 7, rt = r >> 12;
    const int row = rt * 32 + l31, col = kc * 16 + h * 8 + j;
    WXbp[idx] = f2bf(-WX[sec * 32768 + row * 128 + col]);
  } else if (b < 3072) {
    // E0f8p: sections [16*E0_re, -16*E0_im], rows m(1024), cols k(256); 8 dkc/m-tile
    const int idx = (b - 1024) * 256 + threadIdx.x;   // [0, 524288)
    const int sec = idx >> 18, r = idx & 262143;
    const int blk = r >> 10, within = r & 1023;
    const int mt = blk >> 3, dkc = blk & 7;
    const int u = within >> 3, jj = within & 7;
    const int t = u >> 6, h = (u >> 5) & 1, l31 = u & 31;
    const int m = mt * 32 + l31, k = (dkc * 2 + t) * 16 + h * 8 + jj;
    const float v = E0[sec * 262144 + m * 256 + k] * (sec ? -16.f : 16.f);
    E0f8p[idx] = f2fp8(v);
  } else if (b < 5120) {
    // E0Tf8p: sections [16*E0_re^T, -16*E0_im^T], rows k(256), cols m(1024);
    // blocks (rt, c, dkc16)
    const int idx = (b - 3072) * 256 + threadIdx.x;   // [0, 524288)
    const int sec = idx >> 18, r = idx & 262143;
    const int blk = r >> 10, within = r & 1023;
    const int rt = blk >> 5, rem = blk & 31;
    const int c = rem >> 4, dkc = rem & 15;
    const int u = within >> 3, jj = within & 7;
    const int t = u >> 6, h = (u >> 5) & 1, l31 = u & 31;
    const int krow = rt * 32 + l31;
    const int mcol = c * 512 + (dkc * 2 + t) * 16 + h * 8 + jj;
    const float v = E0[sec * 262144 + mcol * 256 + krow] * (sec ? -16.f : 16.f);
    E0Tf8p[idx] = f2fp8(v);
  } else {
    if (threadIdx.x < 3) out[4194304 + threadIdx.x] = 0.f;
  }
}

// ---------------- main fused kernel ----------------
// grid 256 (batch tile of 32), block 512 (8 waves; wave w = row-tile).
// LDS (padded rows, stride % 128B == 8B -> worst 2-way bank aliasing):
//   buf0 [2][32][260]s = 33280B : x bf16; first 16640B aliased as
//                                 zf8 [32][520B] fp8
//   buf1 [2][32][260]s = 33280B : gx bf16 (true scale, Phase D huber)
//   bufy [3][32][132]s = 25344B : y bf16 [y0|y1|-y1]
//   gxf8 [2][32][264B] = 16896B : gx/S fp8 (Phase B B-operand)
//   ring0..2 (3 x 16KB)         : per-wave DMA slots (2KB/wave)
// Total ~154.25KB -> 1 block/CU.

#define RING(s) (((s) % 3) == 0 ? ring0 : ((s) % 3) == 1 ? ring1 : ring2)

__global__ __attribute__((amdgpu_flat_work_group_size(512, 512), amdgpu_waves_per_eu(2, 2)))
void ista_main(
    const float* __restrict__ y,
    const float* __restrict__ etas,
    const float* __restrict__ gammas,
    const short* __restrict__ Cbp,
    const short* __restrict__ WXbp,
    const unsigned char* __restrict__ E0f8p,
    const unsigned char* __restrict__ E0Tf8p,
    float* __restrict__ out) {
  __shared__ short buf0[16640];
  __shared__ short buf1[16640];
  __shared__ short bufy[12672];
  __shared__ unsigned char gxf8[16896];
  __shared__ unsigned char ring0[16384];
  __shared__ unsigned char ring1[16384];
  __shared__ unsigned char ring2[16384];
  unsigned char* zf8 = (unsigned char*)buf0;   // [32][520B] fp8, aliases x-ch0

  const int tid = threadIdx.x;
  const int w = tid >> 6;          // wave 0..7 == row-tile
  const int lane = tid & 63;
  const int l31 = lane & 31;
  const int h = lane >> 5;         // half-wave
  const int b0 = blockIdx.x * 32;
  const int lq = l31 * 8;          // bf16 packed-fragment lane offset (shorts)
  const int lane16 = lane * 16;    // per-lane global DMA offset (bytes)
  const int wslot = w * 2048;      // per-wave ring slot base (bytes)

  // ---- stage y -> bufy: [0]=y_re, [1]=y_im, [2]=-y_im  (rows 132 shorts)
  {
    const int bt = tid >> 4, j = tid & 15;
    const float* yb = y + (size_t)(b0 + bt) * 256;
    #pragma unroll
    for (int rep = 0; rep < 2; rep++) {
      const int jj = j + rep * 16;
      const int ch = jj >> 4, n8 = (jj & 15) << 3;
      const float4 v0 = *(const float4*)(yb + ch * 128 + n8);
      const float4 v1 = *(const float4*)(yb + ch * 128 + n8 + 4);
      s8v pk;
      pk[0] = f2bf(v0.x); pk[1] = f2bf(v0.y); pk[2] = f2bf(v0.z); pk[3] = f2bf(v0.w);
      pk[4] = f2bf(v1.x); pk[5] = f2bf(v1.y); pk[6] = f2bf(v1.z); pk[7] = f2bf(v1.w);
      const int off = bt * 132 + n8;
      *(s8v*)(bufy + ch * 4224 + off) = pk;
      if (ch == 1) {
        s8v nk;
        #pragma unroll
        for (int e = 0; e < 8; e++) nk[e] = pk[e] ^ (short)0x8000;
        *(s8v*)(bufy + 8448 + off) = nk;
      }
    }
  }
  // ---- zero buf0 (x = 0), including pad columns
  {
    s8v z = {0, 0, 0, 0, 0, 0, 0, 0};
    for (int i = tid * 8; i < 16640; i += 4096) *(s8v*)(buf0 + i) = z;
  }
  __syncthreads();

  float ls = 0.f, leq = 0.f, cntf = 0.f;
  float S = 1.f;                   // dynamic scale: gx/S, s/S stored fp8
  float s16_last = 0.0625f;
  f16v xm0, xm1;
  #pragma unroll
  for (int r = 0; r < 16; r++) { xm0[r] = 0.f; xm1[r] = 0.f; }

  #pragma unroll 1
  for (int it = 1; it <= 10; it++) {
    const float gam = gammas[it];
    const float eta = etas[it];
    const float invS = 1.f / S;
    const float s16 = S * 0.0625f;   // accumulator -> true scale (weights x16)
    s16_last = s16;

    // ======== Phase A (bf16): ac = C*x - d~ ; gx = x - gam*ac ========
    f16v ac0, ac1;
    #pragma unroll
    for (int r = 0; r < 16; r++) { ac0[r] = 0.f; ac1[r] = 0.f; }
    #pragma unroll
    for (int kc = 0; kc < 8; kc++) {       // -d~ = (-WX) * y
      const int pa = ((w * 8 + kc) * 2 + h) * 256 + lq;
      const s8v a0 = *(const s8v*)(WXbp + pa);
      const s8v a1 = *(const s8v*)(WXbp + 32768 + pa);
      const int yo = l31 * 132 + ((kc * 2 + h) << 3);
      const s8v by0 = *(const s8v*)(bufy + yo);
      const s8v by1 = *(const s8v*)(bufy + 4224 + yo);
      const s8v by1n = *(const s8v*)(bufy + 8448 + yo);
      ac0 = MFMA(a0, by0, ac0);
      ac0 = MFMA(a1, by1n, ac0);
      ac1 = MFMA(a0, by1, ac1);
      ac1 = MFMA(a1, by0, ac1);
    }
    if (it > 1) {
      #pragma unroll
      for (int kc = 0; kc < 16; kc++) {    // + C * x   (x = 0 at it=1)
        const int pa = ((w * 16 + kc) * 2 + h) * 256 + lq;
        const s8v a0 = *(const s8v*)(Cbp + pa);
        const s8v a1 = *(const s8v*)(Cbp + 65536 + pa);
        const s8v a1n = *(const s8v*)(Cbp + 131072 + pa);
        const int xo = l31 * 260 + ((kc * 2 + h) << 3);
        const s8v bx0 = *(const s8v*)(buf0 + xo);
        const s8v bx1 = *(const s8v*)(buf0 + 8320 + xo);
        ac0 = MFMA(a0, bx0, ac0);
        ac0 = MFMA(a1n, bx1, ac0);
        ac1 = MFMA(a0, bx1, ac1);
        ac1 = MFMA(a1, bx0, ac1);
      }
    }
    // gx = x - gam*ac; write gx bf16 (true) -> buf1, gx*invS fp8 -> gxf8
    #pragma unroll
    for (int r1 = 0; r1 < 4; r1++) {
      const int k0 = w * 32 + 8 * r1 + 4 * h;
      const int idx = l31 * 260 + k0;
      const s4v xv0 = *(const s4v*)(buf0 + idx);
      const s4v xv1 = *(const s4v*)(buf0 + 8320 + idx);
      float g0[4], g1[4];
      s4v p0, p1;
      #pragma unroll
      for (int r0 = 0; r0 < 4; r0++) {
        g0[r0] = bf2f(xv0[r0]) - gam * ac0[r1 * 4 + r0];
        g1[r0] = bf2f(xv1[r0]) - gam * ac1[r1 * 4 + r0];
        p0[r0] = f2bf(g0[r0]);
        p1[r0] = f2bf(g1[r0]);
      }
      *(s4v*)(buf1 + idx) = p0;
      *(s4v*)(buf1 + 8320 + idx) = p1;
      const int ga = l31 * 264 + k0;
      *(int*)(gxf8 + ga) = pk4fp8(g0[0] * invS, g0[1] * invS, g0[2] * invS, g0[3] * invS);
      *(int*)(gxf8 + 8448 + ga) = pk4fp8(g1[0] * invS, g1[1] * invS, g1[2] * invS, g1[3] * invS);
    }
    __syncthreads();

    #pragma unroll
    for (int r = 0; r < 16; r++) { xm0[r] = 0.f; xm1[r] = 0.f; }

    #pragma unroll 1
    for (int c = 0; c < 2; c++) {
      // ---- Phase B (fp8): z = Re(E0 * gx); 2 m-tile passes, 3-slot DMA ring ----
      #pragma unroll 1
      for (int q = 0; q < 2; q++) {
        const int mt = c * 16 + q * 8 + w;
        const unsigned char* gb = E0f8p + (size_t)(mt * 8) * 1024 + lane16;
        f16v zq;
        #pragma unroll
        for (int r = 0; r < 16; r++) zq[r] = 0.f;

#define B_ISSUE(d) do { \
    unsigned char* _s = RING(d) + wslot; \
    glds16(gb + (d) * 1024, _s); \
    glds16(gb + 262144 + (d) * 1024, _s + 1024); \
  } while (0)

        B_ISSUE(0); B_ISSUE(1); B_ISSUE(2);
        #pragma unroll
        for (int dkc = 0; dkc < 8; dkc++) {
          waitvm(2 * (7 - dkc < 2 ? 7 - dkc : 2));
          const unsigned char* Sl = RING(dkc) + wslot;
          __builtin_amdgcn_s_setprio(1);
          #pragma unroll
          for (int t = 0; t < 2; t++) {
            const i64 are = *(const i64*)(Sl + t * 512 + h * 256 + l31 * 8);
            const i64 aim = *(const i64*)(Sl + 1024 + t * 512 + h * 256 + l31 * 8);
            const int kc = dkc * 2 + t;
            const int go = l31 * 264 + (kc << 4) + h * 8;
            const i64 bg0 = *(const i64*)(gxf8 + go);
            const i64 bg1 = *(const i64*)(gxf8 + 8448 + go);
            zq = MFMA8(are, bg0, zq);
            zq = MFMA8(aim, bg1, zq);
          }
          __builtin_amdgcn_s_setprio(0);
          if (dkc + 3 < 8) B_ISSUE(dkc + 3);
        }
#undef B_ISSUE

        // shrink + losses (branch-free); write s*invS fp8 -> zf8 [32][520B]
        const int mtl = q * 8 + w;
        #pragma unroll
        for (int r1 = 0; r1 < 4; r1++) {
          float sv[4];
          #pragma unroll
          for (int r0 = 0; r0 < 4; r0++) {
            const float v = zq[r1 * 4 + r0] * s16;   // true z
            const float av = fabsf(v) - eta;
            const float rs = fmaxf(av, 0.f);
            ls += rs;
            if (it == 10) cntf += (rs > 1e-3f) ? 1.f : 0.f;
            sv[r0] = copysignf(rs, v) * invS;
          }
          const int ml = mtl * 32 + 8 * r1 + 4 * h;
          const int za = l31 * 520 + ml;
          *(int*)(zf8 + za) = pk4fp8(sv[0], sv[1], sv[2], sv[3]);
        }
      }
      __syncthreads();

      // ---- Phase C (fp8): xm += [E0reT; -E0imT] * s, 3-slot DMA ring ----
      {
        const unsigned char* tb = E0Tf8p + (size_t)((w * 2 + c) * 16) * 1024 + lane16;
#define C_ISSUE(d) do { \
    unsigned char* _s = RING(d) + wslot; \
    glds16(tb + (d) * 1024, _s); \
    glds16(tb + 262144 + (d) * 1024, _s + 1024); \
  } while (0)

        C_ISSUE(0); C_ISSUE(1); C_ISSUE(2);
        #pragma unroll
        for (int dkc = 0; dkc < 16; dkc++) {
          waitvm(2 * (15 - dkc < 2 ? 15 - dkc : 2));
          const unsigned char* Sl = RING(dkc) + wslot;
          __builtin_amdgcn_s_setprio(1);
          #pragma unroll
          for (int t = 0; t < 2; t++) {
            const i64 a0 = *(const i64*)(Sl + t * 512 + h * 256 + l31 * 8);
            const i64 a1 = *(const i64*)(Sl + 1024 + t * 512 + h * 256 + l31 * 8);
            const int kc = dkc * 2 + t;
            const i64 bz = *(const i64*)(zf8 + l31 * 520 + (kc << 4) + h * 8);
            xm0 = MFMA8(a0, bz, xm0);
            xm1 = MFMA8(a1, bz, xm1);
          }
          __builtin_amdgcn_s_setprio(0);
          if (dkc + 3 < 16) C_ISSUE(dkc + 3);
        }
#undef C_ISSUE
      }
      __syncthreads();
    }

    // ======== Phase D: huber(gx, xm*s16); x = xm*s16 (bf16) -> buf0 ========
    #pragma unroll
    for (int r1 = 0; r1 < 4; r1++) {
      const int k0 = w * 32 + 8 * r1 + 4 * h;
      const int idx = l31 * 260 + k0;
      const s4v gv0 = *(const s4v*)(buf1 + idx);
      const s4v gv1 = *(const s4v*)(buf1 + 8320 + idx);
      s4v p0, p1;
      #pragma unroll
      for (int r0 = 0; r0 < 4; r0++) {
        const float x0 = xm0[r1 * 4 + r0] * s16, x1 = xm1[r1 * 4 + r0] * s16;
        const float d0 = bf2f(gv0[r0]) - x0;
        const float d1 = bf2f(gv1[r0]) - x1;
        const float a0 = fabsf(d0), a1 = fabsf(d1);
        leq += (a0 < 1.f) ? 0.5f * d0 * d0 : (a0 - 0.5f);
        leq += (a1 < 1.f) ? 0.5f * d1 * d1 : (a1 - 0.5f);
        p0[r0] = f2bf(x0);
        p1[r0] = f2bf(x1);
      }
      *(s4v*)(buf0 + idx) = p0;
      *(s4v*)(buf0 + 8320 + idx) = p1;
    }
    __syncthreads();
    S *= 8.f;   // x grows ~9.3x/iter; keep fp8-stored gx/s near O(1)
  }

  // ---- write x_T (2, 8192, 256) fp32 from final xm (true scale)
  {
    const size_t ob = (size_t)(b0 + l31) * 256;
    #pragma unroll
    for (int r1 = 0; r1 < 4; r1++) {
      const int k0 = w * 32 + 8 * r1 + 4 * h;
      float4 v0, v1;
      v0.x = xm0[r1 * 4 + 0] * s16_last; v0.y = xm0[r1 * 4 + 1] * s16_last;
      v0.z = xm0[r1 * 4 + 2] * s16_last; v0.w = xm0[r1 * 4 + 3] * s16_last;
      v1.x = xm1[r1 * 4 + 0] * s16_last; v1.y = xm1[r1 * 4 + 1] * s16_last;
      v1.z = xm1[r1 * 4 + 2] * s16_last; v1.w = xm1[r1 * 4 + 3] * s16_last;
      *(float4*)(out + ob + k0) = v0;
      *(float4*)(out + 2097152 + ob + k0) = v1;
    }
  }
  // ---- scalar reductions
  #pragma unroll
  for (int off = 32; off > 0; off >>= 1) {
    ls += __shfl_down(ls, off);
    leq += __shfl_down(leq, off);
    cntf += __shfl_down(cntf, off);
  }
  if (lane == 0) {
    atomicAdd(out + 4194304, ls * (1.f / 8192.f));
    atomicAdd(out + 4194305, leq * (1.f / (2.f * 256.f * 8192.f * 10.f)));
    atomicAdd(out + 4194306, cntf * (1.f / 8192.f));
  }
}

extern "C" void kernel_launch(void* const* d_in, const int* in_sizes, int n_in,
                              void* d_out, int out_size, void* d_ws, size_t ws_size,
                              hipStream_t stream) {
  (void)in_sizes; (void)n_in; (void)out_size; (void)ws_size;
  const float* y = (const float*)d_in[0];
  const float* W = (const float*)d_in[1];
  const float* WX = (const float*)d_in[2];
  const float* E0 = (const float*)d_in[3];
  const float* etas = (const float*)d_in[4];
  const float* gammas = (const float*)d_in[5];
  float* out = (float*)d_out;

  short* Cbp = (short*)d_ws;                       // 3 * 65536 shorts
  short* WXbp = Cbp + 196608;                      // 2 * 32768 shorts
  unsigned char* E0f8p = (unsigned char*)(WXbp + 65536);   // 524288 B
  unsigned char* E0Tf8p = E0f8p + 524288;                  // 524288 B (~1.6 MB total)

  prep_all<<<5121, 256, 0, stream>>>(W, WX, E0, Cbp, WXbp, E0f8p, E0Tf8p, out);
  ista_main<<<256, 512, 0, stream>>>(y, etas, gammas, Cbp, WXbp, E0f8p, E0Tf8p, out);
}

// Round 10
// 387.692 us; speedup vs baseline: 1.4060x; 1.0157x over previous
//
#include <hip/hip_runtime.h>
#include <stdint.h>

// ISTA_Net fused MFMA implementation for gfx950.  Round 18:
// R17 base (346us steady; padding + branch-free shrink) + d~ HOIST:
// the WX*y term of Phase A is iteration-invariant -- computed once before
// the it-loop into d0/d1 (32 VGPRs), each iter inits ac = d.  Removes per
// iter: 32 MFMA/wave, 16KB/wave WXbp L2 stream, 24 LDS b128 reads.
// Accumulation order preserved exactly (d accumulates WX terms in the same
// sequence; C terms accumulate on top as before) -> bit-identical results.
// RISK WATCH: extends 32-VGPR live range across B/C (R13's regression
// pattern).  Healthy: VGPR_Count ~160, FETCH ~11MB.  Cliff: VGPR 128 +
// FETCH>50MB -> revert next round.
// Shapes: M=1024, N=128, K=256, T=10, BATCH=8192. LAMBD=1.
// Outputs: x_T(2,8192,256) ++ loss_sparse ++ loss_eq/T ++ out_sparse

typedef short s8v __attribute__((ext_vector_type(8)));   // 8 bf16 MFMA operand
typedef short s4v __attribute__((ext_vector_type(4)));
typedef float f16v __attribute__((ext_vector_type(16))); // 32x32 MFMA accumulator
typedef long long i64;

#define MFMA(a, b, c)  __builtin_amdgcn_mfma_f32_32x32x16_bf16((a), (b), (c), 0, 0, 0)
#define MFMA8(a, b, c) __builtin_amdgcn_mfma_f32_32x32x16_fp8_fp8((a), (b), (c), 0, 0, 0)

__device__ __forceinline__ short f2bf(float f) {
  uint32_t u = __builtin_bit_cast(uint32_t, f);
  u = (u + 0x7FFFu + ((u >> 16) & 1u)) >> 16;   // RNE
  return (short)u;
}
__device__ __forceinline__ float bf2f(short s) {
  uint32_t u = ((uint32_t)(uint16_t)s) << 16;
  return __builtin_bit_cast(float, u);
}
__device__ __forceinline__ unsigned char f2fp8(float v) {
  return (unsigned char)(__builtin_amdgcn_cvt_pk_fp8_f32(v, 0.f, 0, false) & 0xFF);
}
__device__ __forceinline__ int pk4fp8(float a, float b, float c, float d) {
  int r = __builtin_amdgcn_cvt_pk_fp8_f32(a, b, 0, false);
  r = __builtin_amdgcn_cvt_pk_fp8_f32(c, d, r, true);
  return r;
}

// async 16B/lane global->LDS DMA (per-lane gptr; wave-uniform LDS base,
// HW scatters lane i -> base + 16*i)
__device__ __forceinline__ void glds16(const void* g, void* l) {
  __builtin_amdgcn_global_load_lds(
      (const __attribute__((address_space(1))) void*)g,
      (__attribute__((address_space(3))) void*)l, 16, 0, 0);
}
__device__ __forceinline__ void waitvm(int n) {
  if (n <= 0)      asm volatile("s_waitcnt vmcnt(0)" ::: "memory");
  else if (n == 2) asm volatile("s_waitcnt vmcnt(2)" ::: "memory");
  else             asm volatile("s_waitcnt vmcnt(4)" ::: "memory");
}

// ---------------- merged prep kernel ----------------
// bf16 packed layout (Cbp/WXbp): idx = ((tile*KC + kc)*2 + h)*256 + l31*8 + j
// fp8 DMA-block layout (E0f8p/E0Tf8p): per (tile, dkc, sec) 1KB block;
//   byte u*8+jj, u = t*64 + h*32 + l31 -> element (k = (2dkc+t)*16 + h*8 + jj)
// Block ranges: [0,768) Cbp | [768,1024) WXbp | [1024,3072) E0f8p |
//               [3072,5120) E0Tf8p | 5120 zero-tail

__global__ void prep_all(const float* __restrict__ W, const float* __restrict__ WX,
                         const float* __restrict__ E0,
                         short* __restrict__ Cbp, short* __restrict__ WXbp,
                         unsigned char* __restrict__ E0f8p,
                         unsigned char* __restrict__ E0Tf8p,
                         float* __restrict__ out) {
  const int b = blockIdx.x;
  if (b < 768) {
    // Cbp: sections [C0, C1, -C1] (65536 shorts each), C = WX*W (256x256), KC=16
    const int idx = b * 256 + threadIdx.x;
    const int sec = idx >> 16, r = idx & 65535;
    const int j = r & 7, l31 = (r >> 3) & 31, h = (r >> 8) & 1, kc = (r >> 9) & 15, rt = r >> 13;
    const int i = rt * 32 + l31, col = kc * 16 + h * 8 + j;
    float c0 = 0.f, c1 = 0.f;
    for (int n = 0; n < 128; n++) {
      const float wx0 = WX[i * 128 + n], wx1 = WX[32768 + i * 128 + n];
      const float w0 = W[n * 256 + col], w1 = W[32768 + n * 256 + col];
      c0 += wx0 * w0 - wx1 * w1;
      c1 += wx0 * w1 + wx1 * w0;
    }
    Cbp[idx] = f2bf(sec == 0 ? c0 : (sec == 1 ? c1 : -c1));
  } else if (b < 1024) {
    // WXbp: sections [-WX0, -WX1] (32768 shorts each), rows k(256), cols n(128), KC=8
    const int idx = (b - 768) * 256 + threadIdx.x;
    const int sec = idx >> 15, r = idx & 32767;
    const int j = r & 7, l31 = (r >> 3) & 31, h = (r >> 8) & 1, kc = (r >> 9) & 7, rt = r >> 12;
    const int row = rt * 32 + l31, col = kc * 16 + h * 8 + j;
    WXbp[idx] = f2bf(-WX[sec * 32768 + row * 128 + col]);
  } else if (b < 3072) {
    // E0f8p: sections [16*E0_re, -16*E0_im], rows m(1024), cols k(256); 8 dkc/m-tile
    const int idx = (b - 1024) * 256 + threadIdx.x;   // [0, 524288)
    const int sec = idx >> 18, r = idx & 262143;
    const int blk = r >> 10, within = r & 1023;
    const int mt = blk >> 3, dkc = blk & 7;
    const int u = within >> 3, jj = within & 7;
    const int t = u >> 6, h = (u >> 5) & 1, l31 = u & 31;
    const int m = mt * 32 + l31, k = (dkc * 2 + t) * 16 + h * 8 + jj;
    const float v = E0[sec * 262144 + m * 256 + k] * (sec ? -16.f : 16.f);
    E0f8p[idx] = f2fp8(v);
  } else if (b < 5120) {
    // E0Tf8p: sections [16*E0_re^T, -16*E0_im^T], rows k(256), cols m(1024);
    // blocks (rt, c, dkc16)
    const int idx = (b - 3072) * 256 + threadIdx.x;   // [0, 524288)
    const int sec = idx >> 18, r = idx & 262143;
    const int blk = r >> 10, within = r & 1023;
    const int rt = blk >> 5, rem = blk & 31;
    const int c = rem >> 4, dkc = rem & 15;
    const int u = within >> 3, jj = within & 7;
    const int t = u >> 6, h = (u >> 5) & 1, l31 = u & 31;
    const int krow = rt * 32 + l31;
    const int mcol = c * 512 + (dkc * 2 + t) * 16 + h * 8 + jj;
    const float v = E0[sec * 262144 + mcol * 256 + krow] * (sec ? -16.f : 16.f);
    E0Tf8p[idx] = f2fp8(v);
  } else {
    if (threadIdx.x < 3) out[4194304 + threadIdx.x] = 0.f;
  }
}

// ---------------- main fused kernel ----------------
// grid 256 (batch tile of 32), block 512 (8 waves; wave w = row-tile).
// LDS (padded rows, stride % 128B == 8B -> worst 2-way bank aliasing):
//   buf0 [2][32][260]s = 33280B : x bf16; first 16640B aliased as
//                                 zf8 [32][520B] fp8
//   buf1 [2][32][260]s = 33280B : gx bf16 (true scale, Phase D huber)
//   bufy [3][32][132]s = 25344B : y bf16 [y0|y1|-y1]  (used pre-loop only)
//   gxf8 [2][32][264B] = 16896B : gx/S fp8 (Phase B B-operand)
//   ring0..2 (3 x 16KB)         : per-wave DMA slots (2KB/wave)
// Total ~154.25KB -> 1 block/CU.

#define RING(s) (((s) % 3) == 0 ? ring0 : ((s) % 3) == 1 ? ring1 : ring2)

__global__ __attribute__((amdgpu_flat_work_group_size(512, 512), amdgpu_waves_per_eu(2, 2)))
void ista_main(
    const float* __restrict__ y,
    const float* __restrict__ etas,
    const float* __restrict__ gammas,
    const short* __restrict__ Cbp,
    const short* __restrict__ WXbp,
    const unsigned char* __restrict__ E0f8p,
    const unsigned char* __restrict__ E0Tf8p,
    float* __restrict__ out) {
  __shared__ short buf0[16640];
  __shared__ short buf1[16640];
  __shared__ short bufy[12672];
  __shared__ unsigned char gxf8[16896];
  __shared__ unsigned char ring0[16384];
  __shared__ unsigned char ring1[16384];
  __shared__ unsigned char ring2[16384];
  unsigned char* zf8 = (unsigned char*)buf0;   // [32][520B] fp8, aliases x-ch0

  const int tid = threadIdx.x;
  const int w = tid >> 6;          // wave 0..7 == row-tile
  const int lane = tid & 63;
  const int l31 = lane & 31;
  const int h = lane >> 5;         // half-wave
  const int b0 = blockIdx.x * 32;
  const int lq = l31 * 8;          // bf16 packed-fragment lane offset (shorts)
  const int lane16 = lane * 16;    // per-lane global DMA offset (bytes)
  const int wslot = w * 2048;      // per-wave ring slot base (bytes)

  // ---- stage y -> bufy: [0]=y_re, [1]=y_im, [2]=-y_im  (rows 132 shorts)
  {
    const int bt = tid >> 4, j = tid & 15;
    const float* yb = y + (size_t)(b0 + bt) * 256;
    #pragma unroll
    for (int rep = 0; rep < 2; rep++) {
      const int jj = j + rep * 16;
      const int ch = jj >> 4, n8 = (jj & 15) << 3;
      const float4 v0 = *(const float4*)(yb + ch * 128 + n8);
      const float4 v1 = *(const float4*)(yb + ch * 128 + n8 + 4);
      s8v pk;
      pk[0] = f2bf(v0.x); pk[1] = f2bf(v0.y); pk[2] = f2bf(v0.z); pk[3] = f2bf(v0.w);
      pk[4] = f2bf(v1.x); pk[5] = f2bf(v1.y); pk[6] = f2bf(v1.z); pk[7] = f2bf(v1.w);
      const int off = bt * 132 + n8;
      *(s8v*)(bufy + ch * 4224 + off) = pk;
      if (ch == 1) {
        s8v nk;
        #pragma unroll
        for (int e = 0; e < 8; e++) nk[e] = pk[e] ^ (short)0x8000;
        *(s8v*)(bufy + 8448 + off) = nk;
      }
    }
  }
  // ---- zero buf0 (x = 0), including pad columns
  {
    s8v z = {0, 0, 0, 0, 0, 0, 0, 0};
    for (int i = tid * 8; i < 16640; i += 4096) *(s8v*)(buf0 + i) = z;
  }
  __syncthreads();

  // ---- d~ hoist: d = (-WX)*y fragments, iteration-invariant (32 VGPRs)
  f16v d0, d1;
  #pragma unroll
  for (int r = 0; r < 16; r++) { d0[r] = 0.f; d1[r] = 0.f; }
  #pragma unroll
  for (int kc = 0; kc < 8; kc++) {
    const int pa = ((w * 8 + kc) * 2 + h) * 256 + lq;
    const s8v a0 = *(const s8v*)(WXbp + pa);
    const s8v a1 = *(const s8v*)(WXbp + 32768 + pa);
    const int yo = l31 * 132 + ((kc * 2 + h) << 3);
    const s8v by0 = *(const s8v*)(bufy + yo);
    const s8v by1 = *(const s8v*)(bufy + 4224 + yo);
    const s8v by1n = *(const s8v*)(bufy + 8448 + yo);
    d0 = MFMA(a0, by0, d0);
    d0 = MFMA(a1, by1n, d0);
    d1 = MFMA(a0, by1, d1);
    d1 = MFMA(a1, by0, d1);
  }

  float ls = 0.f, leq = 0.f, cntf = 0.f;
  float S = 1.f;                   // dynamic scale: gx/S, s/S stored fp8
  float s16_last = 0.0625f;
  f16v xm0, xm1;
  #pragma unroll
  for (int r = 0; r < 16; r++) { xm0[r] = 0.f; xm1[r] = 0.f; }

  #pragma unroll 1
  for (int it = 1; it <= 10; it++) {
    const float gam = gammas[it];
    const float eta = etas[it];
    const float invS = 1.f / S;
    const float s16 = S * 0.0625f;   // accumulator -> true scale (weights x16)
    s16_last = s16;

    // ======== Phase A (bf16): ac = C*x - d~ ; gx = x - gam*ac ========
    f16v ac0 = d0, ac1 = d1;         // init from hoisted -d~
    if (it > 1) {
      #pragma unroll
      for (int kc = 0; kc < 16; kc++) {    // + C * x   (x = 0 at it=1)
        const int pa = ((w * 16 + kc) * 2 + h) * 256 + lq;
        const s8v a0 = *(const s8v*)(Cbp + pa);
        const s8v a1 = *(const s8v*)(Cbp + 65536 + pa);
        const s8v a1n = *(const s8v*)(Cbp + 131072 + pa);
        const int xo = l31 * 260 + ((kc * 2 + h) << 3);
        const s8v bx0 = *(const s8v*)(buf0 + xo);
        const s8v bx1 = *(const s8v*)(buf0 + 8320 + xo);
        ac0 = MFMA(a0, bx0, ac0);
        ac0 = MFMA(a1n, bx1, ac0);
        ac1 = MFMA(a0, bx1, ac1);
        ac1 = MFMA(a1, bx0, ac1);
      }
    }
    // gx = x - gam*ac; write gx bf16 (true) -> buf1, gx*invS fp8 -> gxf8
    #pragma unroll
    for (int r1 = 0; r1 < 4; r1++) {
      const int k0 = w * 32 + 8 * r1 + 4 * h;
      const int idx = l31 * 260 + k0;
      const s4v xv0 = *(const s4v*)(buf0 + idx);
      const s4v xv1 = *(const s4v*)(buf0 + 8320 + idx);
      float g0[4], g1[4];
      s4v p0, p1;
      #pragma unroll
      for (int r0 = 0; r0 < 4; r0++) {
        g0[r0] = bf2f(xv0[r0]) - gam * ac0[r1 * 4 + r0];
        g1[r0] = bf2f(xv1[r0]) - gam * ac1[r1 * 4 + r0];
        p0[r0] = f2bf(g0[r0]);
        p1[r0] = f2bf(g1[r0]);
      }
      *(s4v*)(buf1 + idx) = p0;
      *(s4v*)(buf1 + 8320 + idx) = p1;
      const int ga = l31 * 264 + k0;
      *(int*)(gxf8 + ga) = pk4fp8(g0[0] * invS, g0[1] * invS, g0[2] * invS, g0[3] * invS);
      *(int*)(gxf8 + 8448 + ga) = pk4fp8(g1[0] * invS, g1[1] * invS, g1[2] * invS, g1[3] * invS);
    }
    __syncthreads();

    #pragma unroll
    for (int r = 0; r < 16; r++) { xm0[r] = 0.f; xm1[r] = 0.f; }

    #pragma unroll 1
    for (int c = 0; c < 2; c++) {
      // ---- Phase B (fp8): z = Re(E0 * gx); 2 m-tile passes, 3-slot DMA ring ----
      #pragma unroll 1
      for (int q = 0; q < 2; q++) {
        const int mt = c * 16 + q * 8 + w;
        const unsigned char* gb = E0f8p + (size_t)(mt * 8) * 1024 + lane16;
        f16v zq;
        #pragma unroll
        for (int r = 0; r < 16; r++) zq[r] = 0.f;

#define B_ISSUE(d) do { \
    unsigned char* _s = RING(d) + wslot; \
    glds16(gb + (d) * 1024, _s); \
    glds16(gb + 262144 + (d) * 1024, _s + 1024); \
  } while (0)

        B_ISSUE(0); B_ISSUE(1); B_ISSUE(2);
        #pragma unroll
        for (int dkc = 0; dkc < 8; dkc++) {
          waitvm(2 * (7 - dkc < 2 ? 7 - dkc : 2));
          const unsigned char* Sl = RING(dkc) + wslot;
          __builtin_amdgcn_s_setprio(1);
          #pragma unroll
          for (int t = 0; t < 2; t++) {
            const i64 are = *(const i64*)(Sl + t * 512 + h * 256 + l31 * 8);
            const i64 aim = *(const i64*)(Sl + 1024 + t * 512 + h * 256 + l31 * 8);
            const int kc = dkc * 2 + t;
            const int go = l31 * 264 + (kc << 4) + h * 8;
            const i64 bg0 = *(const i64*)(gxf8 + go);
            const i64 bg1 = *(const i64*)(gxf8 + 8448 + go);
            zq = MFMA8(are, bg0, zq);
            zq = MFMA8(aim, bg1, zq);
          }
          __builtin_amdgcn_s_setprio(0);
          if (dkc + 3 < 8) B_ISSUE(dkc + 3);
        }
#undef B_ISSUE

        // shrink + losses (branch-free); write s*invS fp8 -> zf8 [32][520B]
        const int mtl = q * 8 + w;
        #pragma unroll
        for (int r1 = 0; r1 < 4; r1++) {
          float sv[4];
          #pragma unroll
          for (int r0 = 0; r0 < 4; r0++) {
            const float v = zq[r1 * 4 + r0] * s16;   // true z
            const float av = fabsf(v) - eta;
            const float rs = fmaxf(av, 0.f);
            ls += rs;
            if (it == 10) cntf += (rs > 1e-3f) ? 1.f : 0.f;
            sv[r0] = copysignf(rs, v) * invS;
          }
          const int ml = mtl * 32 + 8 * r1 + 4 * h;
          const int za = l31 * 520 + ml;
          *(int*)(zf8 + za) = pk4fp8(sv[0], sv[1], sv[2], sv[3]);
        }
      }
      __syncthreads();

      // ---- Phase C (fp8): xm += [E0reT; -E0imT] * s, 3-slot DMA ring ----
      {
        const unsigned char* tb = E0Tf8p + (size_t)((w * 2 + c) * 16) * 1024 + lane16;
#define C_ISSUE(d) do { \
    unsigned char* _s = RING(d) + wslot; \
    glds16(tb + (d) * 1024, _s); \
    glds16(tb + 262144 + (d) * 1024, _s + 1024); \
  } while (0)

        C_ISSUE(0); C_ISSUE(1); C_ISSUE(2);
        #pragma unroll
        for (int dkc = 0; dkc < 16; dkc++) {
          waitvm(2 * (15 - dkc < 2 ? 15 - dkc : 2));
          const unsigned char* Sl = RING(dkc) + wslot;
          __builtin_amdgcn_s_setprio(1);
          #pragma unroll
          for (int t = 0; t < 2; t++) {
            const i64 a0 = *(const i64*)(Sl + t * 512 + h * 256 + l31 * 8);
            const i64 a1 = *(const i64*)(Sl + 1024 + t * 512 + h * 256 + l31 * 8);
            const int kc = dkc * 2 + t;
            const i64 bz = *(const i64*)(zf8 + l31 * 520 + (kc << 4) + h * 8);
            xm0 = MFMA8(a0, bz, xm0);
            xm1 = MFMA8(a1, bz, xm1);
          }
          __builtin_amdgcn_s_setprio(0);
          if (dkc + 3 < 16) C_ISSUE(dkc + 3);
        }
#undef C_ISSUE
      }
      __syncthreads();
    }

    // ======== Phase D: huber(gx, xm*s16); x = xm*s16 (bf16) -> buf0 ========
    #pragma unroll
    for (int r1 = 0; r1 < 4; r1++) {
      const int k0 = w * 32 + 8 * r1 + 4 * h;
      const int idx = l31 * 260 + k0;
      const s4v gv0 = *(const s4v*)(buf1 + idx);
      const s4v gv1 = *(const s4v*)(buf1 + 8320 + idx);
      s4v p0, p1;
      #pragma unroll
      for (int r0 = 0; r0 < 4; r0++) {
        const float x0 = xm0[r1 * 4 + r0] * s16, x1 = xm1[r1 * 4 + r0] * s16;
        const float d0v = bf2f(gv0[r0]) - x0;
        const float d1v = bf2f(gv1[r0]) - x1;
        const float a0 = fabsf(d0v), a1 = fabsf(d1v);
        leq += (a0 < 1.f) ? 0.5f * d0v * d0v : (a0 - 0.5f);
        leq += (a1 < 1.f) ? 0.5f * d1v * d1v : (a1 - 0.5f);
        p0[r0] = f2bf(x0);
        p1[r0] = f2bf(x1);
      }
      *(s4v*)(buf0 + idx) = p0;
      *(s4v*)(buf0 + 8320 + idx) = p1;
    }
    __syncthreads();
    S *= 8.f;   // x grows ~9.3x/iter; keep fp8-stored gx/s near O(1)
  }

  // ---- write x_T (2, 8192, 256) fp32 from final xm (true scale)
  {
    const size_t ob = (size_t)(b0 + l31) * 256;
    #pragma unroll
    for (int r1 = 0; r1 < 4; r1++) {
      const int k0 = w * 32 + 8 * r1 + 4 * h;
      float4 v0, v1;
      v0.x = xm0[r1 * 4 + 0] * s16_last; v0.y = xm0[r1 * 4 + 1] * s16_last;
      v0.z = xm0[r1 * 4 + 2] * s16_last; v0.w = xm0[r1 * 4 + 3] * s16_last;
      v1.x = xm1[r1 * 4 + 0] * s16_last; v1.y = xm1[r1 * 4 + 1] * s16_last;
      v1.z = xm1[r1 * 4 + 2] * s16_last; v1.w = xm1[r1 * 4 + 3] * s16_last;
      *(float4*)(out + ob + k0) = v0;
      *(float4*)(out + 2097152 + ob + k0) = v1;
    }
  }
  // ---- scalar reductions
  #pragma unroll
  for (int off = 32; off > 0; off >>= 1) {
    ls += __shfl_down(ls, off);
    leq += __shfl_down(leq, off);
    cntf += __shfl_down(cntf, off);
  }
  if (lane == 0) {
    atomicAdd(out + 4194304, ls * (1.f / 8192.f));
    atomicAdd(out + 4194305, leq * (1.f / (2.f * 256.f * 8192.f * 10.f)));
    atomicAdd(out + 4194306, cntf * (1.f / 8192.f));
  }
}

extern "C" void kernel_launch(void* const* d_in, const int* in_sizes, int n_in,
                              void* d_out, int out_size, void* d_ws, size_t ws_size,
                              hipStream_t stream) {
  (void)in_sizes; (void)n_in; (void)out_size; (void)ws_size;
  const float* y = (const float*)d_in[0];
  const float* W = (const float*)d_in[1];
  const float* WX = (const float*)d_in[2];
  const float* E0 = (const float*)d_in[3];
  const float* etas = (const float*)d_in[4];
  const float* gammas = (const float*)d_in[5];
  float* out = (float*)d_out;

  short* Cbp = (short*)d_ws;                       // 3 * 65536 shorts
  short* WXbp = Cbp + 196608;                      // 2 * 32768 shorts
  unsigned char* E0f8p = (unsigned char*)(WXbp + 65536);   // 524288 B
  unsigned char* E0Tf8p = E0f8p + 524288;                  // 524288 B (~1.6 MB total)

  prep_all<<<5121, 256, 0, stream>>>(W, WX, E0, Cbp, WXbp, E0f8p, E0Tf8p, out);
  ista_main<<<256, 512, 0, stream>>>(y, etas, gammas, Cbp, WXbp, E0f8p, E0Tf8p, out);
}

// Round 11
// 381.758 us; speedup vs baseline: 1.4278x; 1.0155x over previous
//
#include <hip/hip_runtime.h>
#include <stdint.h>

// ISTA_Net fused MFMA implementation for gfx950.  Round 19:
// R18 base (332.7us steady; padding + branch-free shrink + d~ hoist) +
// -C1 SECTION ELIMINATION: Phase A is L2-BW-bound on the Cbp stream
// (384KB/CU/iter = 7000cyc floor vs 4352cyc MFMA).  The 3rd section (-C1)
// is the 2nd section with the sign flipped; for RNE bf16,
// f2bf(-c) == f2bf(c) ^ 0x8000 exactly -> replace the a1n LOAD with 4
// packed v_xor_b32 on a1.  Bit-identical; stream 48->32KB/wave/iter
// (floor -2333cyc x9 iters ~= 8.7us).  Prep: sec==2 early-out (dead).
// Shapes: M=1024, N=128, K=256, T=10, BATCH=8192. LAMBD=1.
// Outputs: x_T(2,8192,256) ++ loss_sparse ++ loss_eq/T ++ out_sparse

typedef short s8v __attribute__((ext_vector_type(8)));   // 8 bf16 MFMA operand
typedef short s4v __attribute__((ext_vector_type(4)));
typedef float f16v __attribute__((ext_vector_type(16))); // 32x32 MFMA accumulator
typedef long long i64;

#define MFMA(a, b, c)  __builtin_amdgcn_mfma_f32_32x32x16_bf16((a), (b), (c), 0, 0, 0)
#define MFMA8(a, b, c) __builtin_amdgcn_mfma_f32_32x32x16_fp8_fp8((a), (b), (c), 0, 0, 0)

__device__ __forceinline__ short f2bf(float f) {
  uint32_t u = __builtin_bit_cast(uint32_t, f);
  u = (u + 0x7FFFu + ((u >> 16) & 1u)) >> 16;   // RNE
  return (short)u;
}
__device__ __forceinline__ float bf2f(short s) {
  uint32_t u = ((uint32_t)(uint16_t)s) << 16;
  return __builtin_bit_cast(float, u);
}
__device__ __forceinline__ unsigned char f2fp8(float v) {
  return (unsigned char)(__builtin_amdgcn_cvt_pk_fp8_f32(v, 0.f, 0, false) & 0xFF);
}
__device__ __forceinline__ int pk4fp8(float a, float b, float c, float d) {
  int r = __builtin_amdgcn_cvt_pk_fp8_f32(a, b, 0, false);
  r = __builtin_amdgcn_cvt_pk_fp8_f32(c, d, r, true);
  return r;
}

// async 16B/lane global->LDS DMA (per-lane gptr; wave-uniform LDS base,
// HW scatters lane i -> base + 16*i)
__device__ __forceinline__ void glds16(const void* g, void* l) {
  __builtin_amdgcn_global_load_lds(
      (const __attribute__((address_space(1))) void*)g,
      (__attribute__((address_space(3))) void*)l, 16, 0, 0);
}
__device__ __forceinline__ void waitvm(int n) {
  if (n <= 0)      asm volatile("s_waitcnt vmcnt(0)" ::: "memory");
  else if (n == 2) asm volatile("s_waitcnt vmcnt(2)" ::: "memory");
  else             asm volatile("s_waitcnt vmcnt(4)" ::: "memory");
}

// ---------------- merged prep kernel ----------------
// bf16 packed layout (Cbp/WXbp): idx = ((tile*KC + kc)*2 + h)*256 + l31*8 + j
// fp8 DMA-block layout (E0f8p/E0Tf8p): per (tile, dkc, sec) 1KB block;
//   byte u*8+jj, u = t*64 + h*32 + l31 -> element (k = (2dkc+t)*16 + h*8 + jj)
// Block ranges: [0,768) Cbp | [768,1024) WXbp | [1024,3072) E0f8p |
//               [3072,5120) E0Tf8p | 5120 zero-tail
// Cbp sec==2 (-C1) is DEAD since R19 (main XOR-negates a1) -> early-out.

__global__ void prep_all(const float* __restrict__ W, const float* __restrict__ WX,
                         const float* __restrict__ E0,
                         short* __restrict__ Cbp, short* __restrict__ WXbp,
                         unsigned char* __restrict__ E0f8p,
                         unsigned char* __restrict__ E0Tf8p,
                         float* __restrict__ out) {
  const int b = blockIdx.x;
  if (b < 768) {
    // Cbp: sections [C0, C1, (dead)] (65536 shorts each), C = WX*W, KC=16
    const int idx = b * 256 + threadIdx.x;
    const int sec = idx >> 16, r = idx & 65535;
    if (sec == 2) return;   // -C1 never read (main negates via XOR)
    const int j = r & 7, l31 = (r >> 3) & 31, h = (r >> 8) & 1, kc = (r >> 9) & 15, rt = r >> 13;
    const int i = rt * 32 + l31, col = kc * 16 + h * 8 + j;
    float c0 = 0.f, c1 = 0.f;
    for (int n = 0; n < 128; n++) {
      const float wx0 = WX[i * 128 + n], wx1 = WX[32768 + i * 128 + n];
      const float w0 = W[n * 256 + col], w1 = W[32768 + n * 256 + col];
      c0 += wx0 * w0 - wx1 * w1;
      c1 += wx0 * w1 + wx1 * w0;
    }
    Cbp[idx] = f2bf(sec == 0 ? c0 : c1);
  } else if (b < 1024) {
    // WXbp: sections [-WX0, -WX1] (32768 shorts each), rows k(256), cols n(128), KC=8
    const int idx = (b - 768) * 256 + threadIdx.x;
    const int sec = idx >> 15, r = idx & 32767;
    const int j = r & 7, l31 = (r >> 3) & 31, h = (r >> 8) & 1, kc = (r >> 9) & 7, rt = r >> 12;
    const int row = rt * 32 + l31, col = kc * 16 + h * 8 + j;
    WXbp[idx] = f2bf(-WX[sec * 32768 + row * 128 + col]);
  } else if (b < 3072) {
    // E0f8p: sections [16*E0_re, -16*E0_im], rows m(1024), cols k(256); 8 dkc/m-tile
    const int idx = (b - 1024) * 256 + threadIdx.x;   // [0, 524288)
    const int sec = idx >> 18, r = idx & 262143;
    const int blk = r >> 10, within = r & 1023;
    const int mt = blk >> 3, dkc = blk & 7;
    const int u = within >> 3, jj = within & 7;
    const int t = u >> 6, h = (u >> 5) & 1, l31 = u & 31;
    const int m = mt * 32 + l31, k = (dkc * 2 + t) * 16 + h * 8 + jj;
    const float v = E0[sec * 262144 + m * 256 + k] * (sec ? -16.f : 16.f);
    E0f8p[idx] = f2fp8(v);
  } else if (b < 5120) {
    // E0Tf8p: sections [16*E0_re^T, -16*E0_im^T], rows k(256), cols m(1024);
    // blocks (rt, c, dkc16)
    const int idx = (b - 3072) * 256 + threadIdx.x;   // [0, 524288)
    const int sec = idx >> 18, r = idx & 262143;
    const int blk = r >> 10, within = r & 1023;
    const int rt = blk >> 5, rem = blk & 31;
    const int c = rem >> 4, dkc = rem & 15;
    const int u = within >> 3, jj = within & 7;
    const int t = u >> 6, h = (u >> 5) & 1, l31 = u & 31;
    const int krow = rt * 32 + l31;
    const int mcol = c * 512 + (dkc * 2 + t) * 16 + h * 8 + jj;
    const float v = E0[sec * 262144 + mcol * 256 + krow] * (sec ? -16.f : 16.f);
    E0Tf8p[idx] = f2fp8(v);
  } else {
    if (threadIdx.x < 3) out[4194304 + threadIdx.x] = 0.f;
  }
}

// ---------------- main fused kernel ----------------
// grid 256 (batch tile of 32), block 512 (8 waves; wave w = row-tile).
// LDS (padded rows, stride % 128B == 8B -> worst 2-way bank aliasing):
//   buf0 [2][32][260]s = 33280B : x bf16; first 16640B aliased as
//                                 zf8 [32][520B] fp8
//   buf1 [2][32][260]s = 33280B : gx bf16 (true scale, Phase D huber)
//   bufy [3][32][132]s = 25344B : y bf16 [y0|y1|-y1]  (used pre-loop only)
//   gxf8 [2][32][264B] = 16896B : gx/S fp8 (Phase B B-operand)
//   ring0..2 (3 x 16KB)         : per-wave DMA slots (2KB/wave)
// Total ~154.25KB -> 1 block/CU.

#define RING(s) (((s) % 3) == 0 ? ring0 : ((s) % 3) == 1 ? ring1 : ring2)

__global__ __attribute__((amdgpu_flat_work_group_size(512, 512), amdgpu_waves_per_eu(2, 2)))
void ista_main(
    const float* __restrict__ y,
    const float* __restrict__ etas,
    const float* __restrict__ gammas,
    const short* __restrict__ Cbp,
    const short* __restrict__ WXbp,
    const unsigned char* __restrict__ E0f8p,
    const unsigned char* __restrict__ E0Tf8p,
    float* __restrict__ out) {
  __shared__ short buf0[16640];
  __shared__ short buf1[16640];
  __shared__ short bufy[12672];
  __shared__ unsigned char gxf8[16896];
  __shared__ unsigned char ring0[16384];
  __shared__ unsigned char ring1[16384];
  __shared__ unsigned char ring2[16384];
  unsigned char* zf8 = (unsigned char*)buf0;   // [32][520B] fp8, aliases x-ch0

  const int tid = threadIdx.x;
  const int w = tid >> 6;          // wave 0..7 == row-tile
  const int lane = tid & 63;
  const int l31 = lane & 31;
  const int h = lane >> 5;         // half-wave
  const int b0 = blockIdx.x * 32;
  const int lq = l31 * 8;          // bf16 packed-fragment lane offset (shorts)
  const int lane16 = lane * 16;    // per-lane global DMA offset (bytes)
  const int wslot = w * 2048;      // per-wave ring slot base (bytes)

  // ---- stage y -> bufy: [0]=y_re, [1]=y_im, [2]=-y_im  (rows 132 shorts)
  {
    const int bt = tid >> 4, j = tid & 15;
    const float* yb = y + (size_t)(b0 + bt) * 256;
    #pragma unroll
    for (int rep = 0; rep < 2; rep++) {
      const int jj = j + rep * 16;
      const int ch = jj >> 4, n8 = (jj & 15) << 3;
      const float4 v0 = *(const float4*)(yb + ch * 128 + n8);
      const float4 v1 = *(const float4*)(yb + ch * 128 + n8 + 4);
      s8v pk;
      pk[0] = f2bf(v0.x); pk[1] = f2bf(v0.y); pk[2] = f2bf(v0.z); pk[3] = f2bf(v0.w);
      pk[4] = f2bf(v1.x); pk[5] = f2bf(v1.y); pk[6] = f2bf(v1.z); pk[7] = f2bf(v1.w);
      const int off = bt * 132 + n8;
      *(s8v*)(bufy + ch * 4224 + off) = pk;
      if (ch == 1) {
        s8v nk;
        #pragma unroll
        for (int e = 0; e < 8; e++) nk[e] = pk[e] ^ (short)0x8000;
        *(s8v*)(bufy + 8448 + off) = nk;
      }
    }
  }
  // ---- zero buf0 (x = 0), including pad columns
  {
    s8v z = {0, 0, 0, 0, 0, 0, 0, 0};
    for (int i = tid * 8; i < 16640; i += 4096) *(s8v*)(buf0 + i) = z;
  }
  __syncthreads();

  // ---- d~ hoist: d = (-WX)*y fragments, iteration-invariant (32 VGPRs)
  f16v d0, d1;
  #pragma unroll
  for (int r = 0; r < 16; r++) { d0[r] = 0.f; d1[r] = 0.f; }
  #pragma unroll
  for (int kc = 0; kc < 8; kc++) {
    const int pa = ((w * 8 + kc) * 2 + h) * 256 + lq;
    const s8v a0 = *(const s8v*)(WXbp + pa);
    const s8v a1 = *(const s8v*)(WXbp + 32768 + pa);
    const int yo = l31 * 132 + ((kc * 2 + h) << 3);
    const s8v by0 = *(const s8v*)(bufy + yo);
    const s8v by1 = *(const s8v*)(bufy + 4224 + yo);
    const s8v by1n = *(const s8v*)(bufy + 8448 + yo);
    d0 = MFMA(a0, by0, d0);
    d0 = MFMA(a1, by1n, d0);
    d1 = MFMA(a0, by1, d1);
    d1 = MFMA(a1, by0, d1);
  }

  float ls = 0.f, leq = 0.f, cntf = 0.f;
  float S = 1.f;                   // dynamic scale: gx/S, s/S stored fp8
  float s16_last = 0.0625f;
  f16v xm0, xm1;
  #pragma unroll
  for (int r = 0; r < 16; r++) { xm0[r] = 0.f; xm1[r] = 0.f; }

  #pragma unroll 1
  for (int it = 1; it <= 10; it++) {
    const float gam = gammas[it];
    const float eta = etas[it];
    const float invS = 1.f / S;
    const float s16 = S * 0.0625f;   // accumulator -> true scale (weights x16)
    s16_last = s16;

    // ======== Phase A (bf16): ac = C*x - d~ ; gx = x - gam*ac ========
    f16v ac0 = d0, ac1 = d1;         // init from hoisted -d~
    if (it > 1) {
      #pragma unroll
      for (int kc = 0; kc < 16; kc++) {    // + C * x   (x = 0 at it=1)
        const int pa = ((w * 16 + kc) * 2 + h) * 256 + lq;
        const s8v a0 = *(const s8v*)(Cbp + pa);
        const s8v a1 = *(const s8v*)(Cbp + 65536 + pa);
        s8v a1n;                           // -C1 via sign-bit XOR (bit-identical
        #pragma unroll                     // to f2bf(-c1); RNE is sign-symmetric)
        for (int e = 0; e < 8; e++) a1n[e] = a1[e] ^ (short)0x8000;
        const int xo = l31 * 260 + ((kc * 2 + h) << 3);
        const s8v bx0 = *(const s8v*)(buf0 + xo);
        const s8v bx1 = *(const s8v*)(buf0 + 8320 + xo);
        ac0 = MFMA(a0, bx0, ac0);
        ac0 = MFMA(a1n, bx1, ac0);
        ac1 = MFMA(a0, bx1, ac1);
        ac1 = MFMA(a1, bx0, ac1);
      }
    }
    // gx = x - gam*ac; write gx bf16 (true) -> buf1, gx*invS fp8 -> gxf8
    #pragma unroll
    for (int r1 = 0; r1 < 4; r1++) {
      const int k0 = w * 32 + 8 * r1 + 4 * h;
      const int idx = l31 * 260 + k0;
      const s4v xv0 = *(const s4v*)(buf0 + idx);
      const s4v xv1 = *(const s4v*)(buf0 + 8320 + idx);
      float g0[4], g1[4];
      s4v p0, p1;
      #pragma unroll
      for (int r0 = 0; r0 < 4; r0++) {
        g0[r0] = bf2f(xv0[r0]) - gam * ac0[r1 * 4 + r0];
        g1[r0] = bf2f(xv1[r0]) - gam * ac1[r1 * 4 + r0];
        p0[r0] = f2bf(g0[r0]);
        p1[r0] = f2bf(g1[r0]);
      }
      *(s4v*)(buf1 + idx) = p0;
      *(s4v*)(buf1 + 8320 + idx) = p1;
      const int ga = l31 * 264 + k0;
      *(int*)(gxf8 + ga) = pk4fp8(g0[0] * invS, g0[1] * invS, g0[2] * invS, g0[3] * invS);
      *(int*)(gxf8 + 8448 + ga) = pk4fp8(g1[0] * invS, g1[1] * invS, g1[2] * invS, g1[3] * invS);
    }
    __syncthreads();

    #pragma unroll
    for (int r = 0; r < 16; r++) { xm0[r] = 0.f; xm1[r] = 0.f; }

    #pragma unroll 1
    for (int c = 0; c < 2; c++) {
      // ---- Phase B (fp8): z = Re(E0 * gx); 2 m-tile passes, 3-slot DMA ring ----
      #pragma unroll 1
      for (int q = 0; q < 2; q++) {
        const int mt = c * 16 + q * 8 + w;
        const unsigned char* gb = E0f8p + (size_t)(mt * 8) * 1024 + lane16;
        f16v zq;
        #pragma unroll
        for (int r = 0; r < 16; r++) zq[r] = 0.f;

#define B_ISSUE(d) do { \
    unsigned char* _s = RING(d) + wslot; \
    glds16(gb + (d) * 1024, _s); \
    glds16(gb + 262144 + (d) * 1024, _s + 1024); \
  } while (0)

        B_ISSUE(0); B_ISSUE(1); B_ISSUE(2);
        #pragma unroll
        for (int dkc = 0; dkc < 8; dkc++) {
          waitvm(2 * (7 - dkc < 2 ? 7 - dkc : 2));
          const unsigned char* Sl = RING(dkc) + wslot;
          __builtin_amdgcn_s_setprio(1);
          #pragma unroll
          for (int t = 0; t < 2; t++) {
            const i64 are = *(const i64*)(Sl + t * 512 + h * 256 + l31 * 8);
            const i64 aim = *(const i64*)(Sl + 1024 + t * 512 + h * 256 + l31 * 8);
            const int kc = dkc * 2 + t;
            const int go = l31 * 264 + (kc << 4) + h * 8;
            const i64 bg0 = *(const i64*)(gxf8 + go);
            const i64 bg1 = *(const i64*)(gxf8 + 8448 + go);
            zq = MFMA8(are, bg0, zq);
            zq = MFMA8(aim, bg1, zq);
          }
          __builtin_amdgcn_s_setprio(0);
          if (dkc + 3 < 8) B_ISSUE(dkc + 3);
        }
#undef B_ISSUE

        // shrink + losses (branch-free); write s*invS fp8 -> zf8 [32][520B]
        const int mtl = q * 8 + w;
        #pragma unroll
        for (int r1 = 0; r1 < 4; r1++) {
          float sv[4];
          #pragma unroll
          for (int r0 = 0; r0 < 4; r0++) {
            const float v = zq[r1 * 4 + r0] * s16;   // true z
            const float av = fabsf(v) - eta;
            const float rs = fmaxf(av, 0.f);
            ls += rs;
            if (it == 10) cntf += (rs > 1e-3f) ? 1.f : 0.f;
            sv[r0] = copysignf(rs, v) * invS;
          }
          const int ml = mtl * 32 + 8 * r1 + 4 * h;
          const int za = l31 * 520 + ml;
          *(int*)(zf8 + za) = pk4fp8(sv[0], sv[1], sv[2], sv[3]);
        }
      }
      __syncthreads();

      // ---- Phase C (fp8): xm += [E0reT; -E0imT] * s, 3-slot DMA ring ----
      {
        const unsigned char* tb = E0Tf8p + (size_t)((w * 2 + c) * 16) * 1024 + lane16;
#define C_ISSUE(d) do { \
    unsigned char* _s = RING(d) + wslot; \
    glds16(tb + (d) * 1024, _s); \
    glds16(tb + 262144 + (d) * 1024, _s + 1024); \
  } while (0)

        C_ISSUE(0); C_ISSUE(1); C_ISSUE(2);
        #pragma unroll
        for (int dkc = 0; dkc < 16; dkc++) {
          waitvm(2 * (15 - dkc < 2 ? 15 - dkc : 2));
          const unsigned char* Sl = RING(dkc) + wslot;
          __builtin_amdgcn_s_setprio(1);
          #pragma unroll
          for (int t = 0; t < 2; t++) {
            const i64 a0 = *(const i64*)(Sl + t * 512 + h * 256 + l31 * 8);
            const i64 a1 = *(const i64*)(Sl + 1024 + t * 512 + h * 256 + l31 * 8);
            const int kc = dkc * 2 + t;
            const i64 bz = *(const i64*)(zf8 + l31 * 520 + (kc << 4) + h * 8);
            xm0 = MFMA8(a0, bz, xm0);
            xm1 = MFMA8(a1, bz, xm1);
          }
          __builtin_amdgcn_s_setprio(0);
          if (dkc + 3 < 16) C_ISSUE(dkc + 3);
        }
#undef C_ISSUE
      }
      __syncthreads();
    }

    // ======== Phase D: huber(gx, xm*s16); x = xm*s16 (bf16) -> buf0 ========
    #pragma unroll
    for (int r1 = 0; r1 < 4; r1++) {
      const int k0 = w * 32 + 8 * r1 + 4 * h;
      const int idx = l31 * 260 + k0;
      const s4v gv0 = *(const s4v*)(buf1 + idx);
      const s4v gv1 = *(const s4v*)(buf1 + 8320 + idx);
      s4v p0, p1;
      #pragma unroll
      for (int r0 = 0; r0 < 4; r0++) {
        const float x0 = xm0[r1 * 4 + r0] * s16, x1 = xm1[r1 * 4 + r0] * s16;
        const float d0v = bf2f(gv0[r0]) - x0;
        const float d1v = bf2f(gv1[r0]) - x1;
        const float a0 = fabsf(d0v), a1 = fabsf(d1v);
        leq += (a0 < 1.f) ? 0.5f * d0v * d0v : (a0 - 0.5f);
        leq += (a1 < 1.f) ? 0.5f * d1v * d1v : (a1 - 0.5f);
        p0[r0] = f2bf(x0);
        p1[r0] = f2bf(x1);
      }
      *(s4v*)(buf0 + idx) = p0;
      *(s4v*)(buf0 + 8320 + idx) = p1;
    }
    __syncthreads();
    S *= 8.f;   // x grows ~9.3x/iter; keep fp8-stored gx/s near O(1)
  }

  // ---- write x_T (2, 8192, 256) fp32 from final xm (true scale)
  {
    const size_t ob = (size_t)(b0 + l31) * 256;
    #pragma unroll
    for (int r1 = 0; r1 < 4; r1++) {
      const int k0 = w * 32 + 8 * r1 + 4 * h;
      float4 v0, v1;
      v0.x = xm0[r1 * 4 + 0] * s16_last; v0.y = xm0[r1 * 4 + 1] * s16_last;
      v0.z = xm0[r1 * 4 + 2] * s16_last; v0.w = xm0[r1 * 4 + 3] * s16_last;
      v1.x = xm1[r1 * 4 + 0] * s16_last; v1.y = xm1[r1 * 4 + 1] * s16_last;
      v1.z = xm1[r1 * 4 + 2] * s16_last; v1.w = xm1[r1 * 4 + 3] * s16_last;
      *(float4*)(out + ob + k0) = v0;
      *(float4*)(out + 2097152 + ob + k0) = v1;
    }
  }
  // ---- scalar reductions
  #pragma unroll
  for (int off = 32; off > 0; off >>= 1) {
    ls += __shfl_down(ls, off);
    leq += __shfl_down(leq, off);
    cntf += __shfl_down(cntf, off);
  }
  if (lane == 0) {
    atomicAdd(out + 4194304, ls * (1.f / 8192.f));
    atomicAdd(out + 4194305, leq * (1.f / (2.f * 256.f * 8192.f * 10.f)));
    atomicAdd(out + 4194306, cntf * (1.f / 8192.f));
  }
}

extern "C" void kernel_launch(void* const* d_in, const int* in_sizes, int n_in,
                              void* d_out, int out_size, void* d_ws, size_t ws_size,
                              hipStream_t stream) {
  (void)in_sizes; (void)n_in; (void)out_size; (void)ws_size;
  const float* y = (const float*)d_in[0];
  const float* W = (const float*)d_in[1];
  const float* WX = (const float*)d_in[2];
  const float* E0 = (const float*)d_in[3];
  const float* etas = (const float*)d_in[4];
  const float* gammas = (const float*)d_in[5];
  float* out = (float*)d_out;

  short* Cbp = (short*)d_ws;                       // 3 * 65536 shorts (sec2 dead)
  short* WXbp = Cbp + 196608;                      // 2 * 32768 shorts
  unsigned char* E0f8p = (unsigned char*)(WXbp + 65536);   // 524288 B
  unsigned char* E0Tf8p = E0f8p + 524288;                  // 524288 B (~1.6 MB total)

  prep_all<<<5121, 256, 0, stream>>>(W, WX, E0, Cbp, WXbp, E0f8p, E0Tf8p, out);
  ista_main<<<256, 512, 0, stream>>>(y, etas, gammas, Cbp, WXbp, E0f8p, E0Tf8p, out);
}

// Round 12
// 373.621 us; speedup vs baseline: 1.4589x; 1.0218x over previous
//
#include <hip/hip_runtime.h>
#include <stdint.h>

// ISTA_Net fused MFMA implementation for gfx950.  Round 20:
// ista_main UNTOUCHED from R19 (329.7us steady; padding + branch-free
// shrink + d~ hoist + XOR-negated C1).  This round attacks prep_all
// (~52us = 13.6% of 381.8 total):
// - Cbp branch was latency-bound: 128-deep scalar dot with strided global
//   W loads (~200cyc L2 hits, serial).  Now LDS-staged: WX rows [2][32][132]
//   (padded, conflict-free broadcast reads) + W cols [2][128][8], coalesced
//   float4 staging, then the IDENTICAL scalar accumulation from LDS
//   (bit-identical data + same n-order -> bit-identical Cbp).
// - sec0/sec1 blocks did identical work (only the store differed): merged,
//   each block stores both c0 and c1.  Cbp work halved.
// - Grid 5121 -> 4609 (dead -C1 blocks removed).
// Shapes: M=1024, N=128, K=256, T=10, BATCH=8192. LAMBD=1.
// Outputs: x_T(2,8192,256) ++ loss_sparse ++ loss_eq/T ++ out_sparse

typedef short s8v __attribute__((ext_vector_type(8)));   // 8 bf16 MFMA operand
typedef short s4v __attribute__((ext_vector_type(4)));
typedef float f16v __attribute__((ext_vector_type(16))); // 32x32 MFMA accumulator
typedef long long i64;

#define MFMA(a, b, c)  __builtin_amdgcn_mfma_f32_32x32x16_bf16((a), (b), (c), 0, 0, 0)
#define MFMA8(a, b, c) __builtin_amdgcn_mfma_f32_32x32x16_fp8_fp8((a), (b), (c), 0, 0, 0)

__device__ __forceinline__ short f2bf(float f) {
  uint32_t u = __builtin_bit_cast(uint32_t, f);
  u = (u + 0x7FFFu + ((u >> 16) & 1u)) >> 16;   // RNE
  return (short)u;
}
__device__ __forceinline__ float bf2f(short s) {
  uint32_t u = ((uint32_t)(uint16_t)s) << 16;
  return __builtin_bit_cast(float, u);
}
__device__ __forceinline__ unsigned char f2fp8(float v) {
  return (unsigned char)(__builtin_amdgcn_cvt_pk_fp8_f32(v, 0.f, 0, false) & 0xFF);
}
__device__ __forceinline__ int pk4fp8(float a, float b, float c, float d) {
  int r = __builtin_amdgcn_cvt_pk_fp8_f32(a, b, 0, false);
  r = __builtin_amdgcn_cvt_pk_fp8_f32(c, d, r, true);
  return r;
}

// async 16B/lane global->LDS DMA (per-lane gptr; wave-uniform LDS base,
// HW scatters lane i -> base + 16*i)
__device__ __forceinline__ void glds16(const void* g, void* l) {
  __builtin_amdgcn_global_load_lds(
      (const __attribute__((address_space(1))) void*)g,
      (__attribute__((address_space(3))) void*)l, 16, 0, 0);
}
__device__ __forceinline__ void waitvm(int n) {
  if (n <= 0)      asm volatile("s_waitcnt vmcnt(0)" ::: "memory");
  else if (n == 2) asm volatile("s_waitcnt vmcnt(2)" ::: "memory");
  else             asm volatile("s_waitcnt vmcnt(4)" ::: "memory");
}

// ---------------- merged prep kernel ----------------
// Grid 4609:
//   [0,256)    Cbp via LDS staging (both sections per block)
//   [256,512)  WXbp
//   [512,2560) E0f8p
//   [2560,4608) E0Tf8p
//   4608       zero-tail
// bf16 packed layout (Cbp/WXbp): idx = ((tile*KC + kc)*2 + h)*256 + l31*8 + j
// fp8 DMA-block layout (E0f8p/E0Tf8p): per (tile, dkc, sec) 1KB block;
//   byte u*8+jj, u = t*64 + h*32 + l31 -> element (k = (2dkc+t)*16 + h*8 + jj)

__global__ void prep_all(const float* __restrict__ W, const float* __restrict__ WX,
                         const float* __restrict__ E0,
                         short* __restrict__ Cbp, short* __restrict__ WXbp,
                         unsigned char* __restrict__ E0f8p,
                         unsigned char* __restrict__ E0Tf8p,
                         float* __restrict__ out) {
  const int b = blockIdx.x;
  if (b < 256) {
    // Cbp: block = rt(3b)<<5 | kc(4b)<<1 | h; computes C0 and C1 for
    // rows rt*32+[0,32), cols kc*16+h*8+[0,8).  C = WX*W (complex).
    const int rt = b >> 5, kc = (b >> 1) & 15, h = b & 1;
    const int tid = threadIdx.x;
    const int j = tid & 7, l31 = tid >> 3;        // l31 in [0,32)
    const int col0 = kc * 16 + h * 8;
    __shared__ float lWX[2][32][132];             // +4 pad: conflict-free bcast
    __shared__ float lW[2][128][8];
    #pragma unroll
    for (int ch = 0; ch < 2; ch++) {
      #pragma unroll
      for (int r = 0; r < 4; r++) {
        const int v = r * 256 + tid;
        const int n4 = v & 31, row = v >> 5;
        *(float4*)&lWX[ch][row][n4 * 4] =
            *(const float4*)(WX + ch * 32768 + (rt * 32 + row) * 128 + n4 * 4);
      }
      const int n = tid >> 1, half = tid & 1;
      *(float4*)&lW[ch][n][half * 4] =
          *(const float4*)(W + ch * 32768 + n * 256 + col0 + half * 4);
    }
    __syncthreads();
    float c0 = 0.f, c1 = 0.f;
    for (int n = 0; n < 128; n++) {
      const float wx0 = lWX[0][l31][n], wx1 = lWX[1][l31][n];
      const float w0 = lW[0][n][j], w1 = lW[1][n][j];
      c0 += wx0 * w0 - wx1 * w1;
      c1 += wx0 * w1 + wx1 * w0;
    }
    const int idx = b * 256 + tid;
    Cbp[idx] = f2bf(c0);
    Cbp[65536 + idx] = f2bf(c1);
  } else if (b < 512) {
    // WXbp: sections [-WX0, -WX1] (32768 shorts each), rows k(256), cols n(128), KC=8
    const int idx = (b - 256) * 256 + threadIdx.x;
    const int sec = idx >> 15, r = idx & 32767;
    const int j = r & 7, l31 = (r >> 3) & 31, h = (r >> 8) & 1, kc = (r >> 9) & 7, rt = r >> 12;
    const int row = rt * 32 + l31, col = kc * 16 + h * 8 + j;
    WXbp[idx] = f2bf(-WX[sec * 32768 + row * 128 + col]);
  } else if (b < 2560) {
    // E0f8p: sections [16*E0_re, -16*E0_im], rows m(1024), cols k(256); 8 dkc/m-tile
    const int idx = (b - 512) * 256 + threadIdx.x;   // [0, 524288)
    const int sec = idx >> 18, r = idx & 262143;
    const int blk = r >> 10, within = r & 1023;
    const int mt = blk >> 3, dkc = blk & 7;
    const int u = within >> 3, jj = within & 7;
    const int t = u >> 6, h = (u >> 5) & 1, l31 = u & 31;
    const int m = mt * 32 + l31, k = (dkc * 2 + t) * 16 + h * 8 + jj;
    const float v = E0[sec * 262144 + m * 256 + k] * (sec ? -16.f : 16.f);
    E0f8p[idx] = f2fp8(v);
  } else if (b < 4608) {
    // E0Tf8p: sections [16*E0_re^T, -16*E0_im^T], rows k(256), cols m(1024);
    // blocks (rt, c, dkc16)
    const int idx = (b - 2560) * 256 + threadIdx.x;   // [0, 524288)
    const int sec = idx >> 18, r = idx & 262143;
    const int blk = r >> 10, within = r & 1023;
    const int rt = blk >> 5, rem = blk & 31;
    const int c = rem >> 4, dkc = rem & 15;
    const int u = within >> 3, jj = within & 7;
    const int t = u >> 6, h = (u >> 5) & 1, l31 = u & 31;
    const int krow = rt * 32 + l31;
    const int mcol = c * 512 + (dkc * 2 + t) * 16 + h * 8 + jj;
    const float v = E0[sec * 262144 + mcol * 256 + krow] * (sec ? -16.f : 16.f);
    E0Tf8p[idx] = f2fp8(v);
  } else {
    if (threadIdx.x < 3) out[4194304 + threadIdx.x] = 0.f;
  }
}

// ---------------- main fused kernel ----------------
// grid 256 (batch tile of 32), block 512 (8 waves; wave w = row-tile).
// LDS (padded rows, stride % 128B == 8B -> worst 2-way bank aliasing):
//   buf0 [2][32][260]s = 33280B : x bf16; first 16640B aliased as
//                                 zf8 [32][520B] fp8
//   buf1 [2][32][260]s = 33280B : gx bf16 (true scale, Phase D huber)
//   bufy [3][32][132]s = 25344B : y bf16 [y0|y1|-y1]  (used pre-loop only)
//   gxf8 [2][32][264B] = 16896B : gx/S fp8 (Phase B B-operand)
//   ring0..2 (3 x 16KB)         : per-wave DMA slots (2KB/wave)
// Total ~154.25KB -> 1 block/CU.

#define RING(s) (((s) % 3) == 0 ? ring0 : ((s) % 3) == 1 ? ring1 : ring2)

__global__ __attribute__((amdgpu_flat_work_group_size(512, 512), amdgpu_waves_per_eu(2, 2)))
void ista_main(
    const float* __restrict__ y,
    const float* __restrict__ etas,
    const float* __restrict__ gammas,
    const short* __restrict__ Cbp,
    const short* __restrict__ WXbp,
    const unsigned char* __restrict__ E0f8p,
    const unsigned char* __restrict__ E0Tf8p,
    float* __restrict__ out) {
  __shared__ short buf0[16640];
  __shared__ short buf1[16640];
  __shared__ short bufy[12672];
  __shared__ unsigned char gxf8[16896];
  __shared__ unsigned char ring0[16384];
  __shared__ unsigned char ring1[16384];
  __shared__ unsigned char ring2[16384];
  unsigned char* zf8 = (unsigned char*)buf0;   // [32][520B] fp8, aliases x-ch0

  const int tid = threadIdx.x;
  const int w = tid >> 6;          // wave 0..7 == row-tile
  const int lane = tid & 63;
  const int l31 = lane & 31;
  const int h = lane >> 5;         // half-wave
  const int b0 = blockIdx.x * 32;
  const int lq = l31 * 8;          // bf16 packed-fragment lane offset (shorts)
  const int lane16 = lane * 16;    // per-lane global DMA offset (bytes)
  const int wslot = w * 2048;      // per-wave ring slot base (bytes)

  // ---- stage y -> bufy: [0]=y_re, [1]=y_im, [2]=-y_im  (rows 132 shorts)
  {
    const int bt = tid >> 4, j = tid & 15;
    const float* yb = y + (size_t)(b0 + bt) * 256;
    #pragma unroll
    for (int rep = 0; rep < 2; rep++) {
      const int jj = j + rep * 16;
      const int ch = jj >> 4, n8 = (jj & 15) << 3;
      const float4 v0 = *(const float4*)(yb + ch * 128 + n8);
      const float4 v1 = *(const float4*)(yb + ch * 128 + n8 + 4);
      s8v pk;
      pk[0] = f2bf(v0.x); pk[1] = f2bf(v0.y); pk[2] = f2bf(v0.z); pk[3] = f2bf(v0.w);
      pk[4] = f2bf(v1.x); pk[5] = f2bf(v1.y); pk[6] = f2bf(v1.z); pk[7] = f2bf(v1.w);
      const int off = bt * 132 + n8;
      *(s8v*)(bufy + ch * 4224 + off) = pk;
      if (ch == 1) {
        s8v nk;
        #pragma unroll
        for (int e = 0; e < 8; e++) nk[e] = pk[e] ^ (short)0x8000;
        *(s8v*)(bufy + 8448 + off) = nk;
      }
    }
  }
  // ---- zero buf0 (x = 0), including pad columns
  {
    s8v z = {0, 0, 0, 0, 0, 0, 0, 0};
    for (int i = tid * 8; i < 16640; i += 4096) *(s8v*)(buf0 + i) = z;
  }
  __syncthreads();

  // ---- d~ hoist: d = (-WX)*y fragments, iteration-invariant (32 VGPRs)
  f16v d0, d1;
  #pragma unroll
  for (int r = 0; r < 16; r++) { d0[r] = 0.f; d1[r] = 0.f; }
  #pragma unroll
  for (int kc = 0; kc < 8; kc++) {
    const int pa = ((w * 8 + kc) * 2 + h) * 256 + lq;
    const s8v a0 = *(const s8v*)(WXbp + pa);
    const s8v a1 = *(const s8v*)(WXbp + 32768 + pa);
    const int yo = l31 * 132 + ((kc * 2 + h) << 3);
    const s8v by0 = *(const s8v*)(bufy + yo);
    const s8v by1 = *(const s8v*)(bufy + 4224 + yo);
    const s8v by1n = *(const s8v*)(bufy + 8448 + yo);
    d0 = MFMA(a0, by0, d0);
    d0 = MFMA(a1, by1n, d0);
    d1 = MFMA(a0, by1, d1);
    d1 = MFMA(a1, by0, d1);
  }

  float ls = 0.f, leq = 0.f, cntf = 0.f;
  float S = 1.f;                   // dynamic scale: gx/S, s/S stored fp8
  float s16_last = 0.0625f;
  f16v xm0, xm1;
  #pragma unroll
  for (int r = 0; r < 16; r++) { xm0[r] = 0.f; xm1[r] = 0.f; }

  #pragma unroll 1
  for (int it = 1; it <= 10; it++) {
    const float gam = gammas[it];
    const float eta = etas[it];
    const float invS = 1.f / S;
    const float s16 = S * 0.0625f;   // accumulator -> true scale (weights x16)
    s16_last = s16;

    // ======== Phase A (bf16): ac = C*x - d~ ; gx = x - gam*ac ========
    f16v ac0 = d0, ac1 = d1;         // init from hoisted -d~
    if (it > 1) {
      #pragma unroll
      for (int kc = 0; kc < 16; kc++) {    // + C * x   (x = 0 at it=1)
        const int pa = ((w * 16 + kc) * 2 + h) * 256 + lq;
        const s8v a0 = *(const s8v*)(Cbp + pa);
        const s8v a1 = *(const s8v*)(Cbp + 65536 + pa);
        s8v a1n;                           // -C1 via sign-bit XOR (bit-identical
        #pragma unroll                     // to f2bf(-c1); RNE is sign-symmetric)
        for (int e = 0; e < 8; e++) a1n[e] = a1[e] ^ (short)0x8000;
        const int xo = l31 * 260 + ((kc * 2 + h) << 3);
        const s8v bx0 = *(const s8v*)(buf0 + xo);
        const s8v bx1 = *(const s8v*)(buf0 + 8320 + xo);
        ac0 = MFMA(a0, bx0, ac0);
        ac0 = MFMA(a1n, bx1, ac0);
        ac1 = MFMA(a0, bx1, ac1);
        ac1 = MFMA(a1, bx0, ac1);
      }
    }
    // gx = x - gam*ac; write gx bf16 (true) -> buf1, gx*invS fp8 -> gxf8
    #pragma unroll
    for (int r1 = 0; r1 < 4; r1++) {
      const int k0 = w * 32 + 8 * r1 + 4 * h;
      const int idx = l31 * 260 + k0;
      const s4v xv0 = *(const s4v*)(buf0 + idx);
      const s4v xv1 = *(const s4v*)(buf0 + 8320 + idx);
      float g0[4], g1[4];
      s4v p0, p1;
      #pragma unroll
      for (int r0 = 0; r0 < 4; r0++) {
        g0[r0] = bf2f(xv0[r0]) - gam * ac0[r1 * 4 + r0];
        g1[r0] = bf2f(xv1[r0]) - gam * ac1[r1 * 4 + r0];
        p0[r0] = f2bf(g0[r0]);
        p1[r0] = f2bf(g1[r0]);
      }
      *(s4v*)(buf1 + idx) = p0;
      *(s4v*)(buf1 + 8320 + idx) = p1;
      const int ga = l31 * 264 + k0;
      *(int*)(gxf8 + ga) = pk4fp8(g0[0] * invS, g0[1] * invS, g0[2] * invS, g0[3] * invS);
      *(int*)(gxf8 + 8448 + ga) = pk4fp8(g1[0] * invS, g1[1] * invS, g1[2] * invS, g1[3] * invS);
    }
    __syncthreads();

    #pragma unroll
    for (int r = 0; r < 16; r++) { xm0[r] = 0.f; xm1[r] = 0.f; }

    #pragma unroll 1
    for (int c = 0; c < 2; c++) {
      // ---- Phase B (fp8): z = Re(E0 * gx); 2 m-tile passes, 3-slot DMA ring ----
      #pragma unroll 1
      for (int q = 0; q < 2; q++) {
        const int mt = c * 16 + q * 8 + w;
        const unsigned char* gb = E0f8p + (size_t)(mt * 8) * 1024 + lane16;
        f16v zq;
        #pragma unroll
        for (int r = 0; r < 16; r++) zq[r] = 0.f;

#define B_ISSUE(d) do { \
    unsigned char* _s = RING(d) + wslot; \
    glds16(gb + (d) * 1024, _s); \
    glds16(gb + 262144 + (d) * 1024, _s + 1024); \
  } while (0)

        B_ISSUE(0); B_ISSUE(1); B_ISSUE(2);
        #pragma unroll
        for (int dkc = 0; dkc < 8; dkc++) {
          waitvm(2 * (7 - dkc < 2 ? 7 - dkc : 2));
          const unsigned char* Sl = RING(dkc) + wslot;
          __builtin_amdgcn_s_setprio(1);
          #pragma unroll
          for (int t = 0; t < 2; t++) {
            const i64 are = *(const i64*)(Sl + t * 512 + h * 256 + l31 * 8);
            const i64 aim = *(const i64*)(Sl + 1024 + t * 512 + h * 256 + l31 * 8);
            const int kc = dkc * 2 + t;
            const int go = l31 * 264 + (kc << 4) + h * 8;
            const i64 bg0 = *(const i64*)(gxf8 + go);
            const i64 bg1 = *(const i64*)(gxf8 + 8448 + go);
            zq = MFMA8(are, bg0, zq);
            zq = MFMA8(aim, bg1, zq);
          }
          __builtin_amdgcn_s_setprio(0);
          if (dkc + 3 < 8) B_ISSUE(dkc + 3);
        }
#undef B_ISSUE

        // shrink + losses (branch-free); write s*invS fp8 -> zf8 [32][520B]
        const int mtl = q * 8 + w;
        #pragma unroll
        for (int r1 = 0; r1 < 4; r1++) {
          float sv[4];
          #pragma unroll
          for (int r0 = 0; r0 < 4; r0++) {
            const float v = zq[r1 * 4 + r0] * s16;   // true z
            const float av = fabsf(v) - eta;
            const float rs = fmaxf(av, 0.f);
            ls += rs;
            if (it == 10) cntf += (rs > 1e-3f) ? 1.f : 0.f;
            sv[r0] = copysignf(rs, v) * invS;
          }
          const int ml = mtl * 32 + 8 * r1 + 4 * h;
          const int za = l31 * 520 + ml;
          *(int*)(zf8 + za) = pk4fp8(sv[0], sv[1], sv[2], sv[3]);
        }
      }
      __syncthreads();

      // ---- Phase C (fp8): xm += [E0reT; -E0imT] * s, 3-slot DMA ring ----
      {
        const unsigned char* tb = E0Tf8p + (size_t)((w * 2 + c) * 16) * 1024 + lane16;
#define C_ISSUE(d) do { \
    unsigned char* _s = RING(d) + wslot; \
    glds16(tb + (d) * 1024, _s); \
    glds16(tb + 262144 + (d) * 1024, _s + 1024); \
  } while (0)

        C_ISSUE(0); C_ISSUE(1); C_ISSUE(2);
        #pragma unroll
        for (int dkc = 0; dkc < 16; dkc++) {
          waitvm(2 * (15 - dkc < 2 ? 15 - dkc : 2));
          const unsigned char* Sl = RING(dkc) + wslot;
          __builtin_amdgcn_s_setprio(1);
          #pragma unroll
          for (int t = 0; t < 2; t++) {
            const i64 a0 = *(const i64*)(Sl + t * 512 + h * 256 + l31 * 8);
            const i64 a1 = *(const i64*)(Sl + 1024 + t * 512 + h * 256 + l31 * 8);
            const int kc = dkc * 2 + t;
            const i64 bz = *(const i64*)(zf8 + l31 * 520 + (kc << 4) + h * 8);
            xm0 = MFMA8(a0, bz, xm0);
            xm1 = MFMA8(a1, bz, xm1);
          }
          __builtin_amdgcn_s_setprio(0);
          if (dkc + 3 < 16) C_ISSUE(dkc + 3);
        }
#undef C_ISSUE
      }
      __syncthreads();
    }

    // ======== Phase D: huber(gx, xm*s16); x = xm*s16 (bf16) -> buf0 ========
    #pragma unroll
    for (int r1 = 0; r1 < 4; r1++) {
      const int k0 = w * 32 + 8 * r1 + 4 * h;
      const int idx = l31 * 260 + k0;
      const s4v gv0 = *(const s4v*)(buf1 + idx);
      const s4v gv1 = *(const s4v*)(buf1 + 8320 + idx);
      s4v p0, p1;
      #pragma unroll
      for (int r0 = 0; r0 < 4; r0++) {
        const float x0 = xm0[r1 * 4 + r0] * s16, x1 = xm1[r1 * 4 + r0] * s16;
        const float d0v = bf2f(gv0[r0]) - x0;
        const float d1v = bf2f(gv1[r0]) - x1;
        const float a0 = fabsf(d0v), a1 = fabsf(d1v);
        leq += (a0 < 1.f) ? 0.5f * d0v * d0v : (a0 - 0.5f);
        leq += (a1 < 1.f) ? 0.5f * d1v * d1v : (a1 - 0.5f);
        p0[r0] = f2bf(x0);
        p1[r0] = f2bf(x1);
      }
      *(s4v*)(buf0 + idx) = p0;
      *(s4v*)(buf0 + 8320 + idx) = p1;
    }
    __syncthreads();
    S *= 8.f;   // x grows ~9.3x/iter; keep fp8-stored gx/s near O(1)
  }

  // ---- write x_T (2, 8192, 256) fp32 from final xm (true scale)
  {
    const size_t ob = (size_t)(b0 + l31) * 256;
    #pragma unroll
    for (int r1 = 0; r1 < 4; r1++) {
      const int k0 = w * 32 + 8 * r1 + 4 * h;
      float4 v0, v1;
      v0.x = xm0[r1 * 4 + 0] * s16_last; v0.y = xm0[r1 * 4 + 1] * s16_last;
      v0.z = xm0[r1 * 4 + 2] * s16_last; v0.w = xm0[r1 * 4 + 3] * s16_last;
      v1.x = xm1[r1 * 4 + 0] * s16_last; v1.y = xm1[r1 * 4 + 1] * s16_last;
      v1.z = xm1[r1 * 4 + 2] * s16_last; v1.w = xm1[r1 * 4 + 3] * s16_last;
      *(float4*)(out + ob + k0) = v0;
      *(float4*)(out + 2097152 + ob + k0) = v1;
    }
  }
  // ---- scalar reductions
  #pragma unroll
  for (int off = 32; off > 0; off >>= 1) {
    ls += __shfl_down(ls, off);
    leq += __shfl_down(leq, off);
    cntf += __shfl_down(cntf, off);
  }
  if (lane == 0) {
    atomicAdd(out + 4194304, ls * (1.f / 8192.f));
    atomicAdd(out + 4194305, leq * (1.f / (2.f * 256.f * 8192.f * 10.f)));
    atomicAdd(out + 4194306, cntf * (1.f / 8192.f));
  }
}

extern "C" void kernel_launch(void* const* d_in, const int* in_sizes, int n_in,
                              void* d_out, int out_size, void* d_ws, size_t ws_size,
                              hipStream_t stream) {
  (void)in_sizes; (void)n_in; (void)out_size; (void)ws_size;
  const float* y = (const float*)d_in[0];
  const float* W = (const float*)d_in[1];
  const float* WX = (const float*)d_in[2];
  const float* E0 = (const float*)d_in[3];
  const float* etas = (const float*)d_in[4];
  const float* gammas = (const float*)d_in[5];
  float* out = (float*)d_out;

  short* Cbp = (short*)d_ws;                       // 2 * 65536 shorts used
  short* WXbp = Cbp + 196608;                      // 2 * 32768 shorts
  unsigned char* E0f8p = (unsigned char*)(WXbp + 65536);   // 524288 B
  unsigned char* E0Tf8p = E0f8p + 524288;                  // 524288 B (~1.6 MB total)

  prep_all<<<4609, 256, 0, stream>>>(W, WX, E0, Cbp, WXbp, E0f8p, E0Tf8p, out);
  ista_main<<<256, 512, 0, stream>>>(y, etas, gammas, Cbp, WXbp, E0f8p, E0Tf8p, out);
}

// Round 13
// 372.485 us; speedup vs baseline: 1.4634x; 1.0031x over previous
//
#include <hip/hip_runtime.h>
#include <stdint.h>

// ISTA_Net fused MFMA implementation for gfx950.  Round 21:
// R20 base (331.2us steady ista; prep ~42us) + 4-SLOT RING (isolated):
// B/C ring steps measured ~900cyc vs 290cyc L2-supply floor -> latency
// bound at 2-ahead prefetch.  R10-R13 never isolated ring depth on a
// healthy base (gx-in-VGPR confounded it).  bufy (25KB) is DEAD inside
// the it-loop since the R18 d~ hoist -> ring3 aliases bufy: 4 slots,
// 3-ahead prefetch, zero LDS growth.  Pass-local issue only (cross-pass
// pre-issue stays banned -- that was R16's convoy breaker).
// waitvm schedule: B: dkc<=4?6:5->4:6->2:7->0.  C: dkc<=12?6:13->4:14->2:15->0.
// Shapes: M=1024, N=128, K=256, T=10, BATCH=8192. LAMBD=1.
// Outputs: x_T(2,8192,256) ++ loss_sparse ++ loss_eq/T ++ out_sparse

typedef short s8v __attribute__((ext_vector_type(8)));   // 8 bf16 MFMA operand
typedef short s4v __attribute__((ext_vector_type(4)));
typedef float f16v __attribute__((ext_vector_type(16))); // 32x32 MFMA accumulator
typedef long long i64;

#define MFMA(a, b, c)  __builtin_amdgcn_mfma_f32_32x32x16_bf16((a), (b), (c), 0, 0, 0)
#define MFMA8(a, b, c) __builtin_amdgcn_mfma_f32_32x32x16_fp8_fp8((a), (b), (c), 0, 0, 0)

__device__ __forceinline__ short f2bf(float f) {
  uint32_t u = __builtin_bit_cast(uint32_t, f);
  u = (u + 0x7FFFu + ((u >> 16) & 1u)) >> 16;   // RNE
  return (short)u;
}
__device__ __forceinline__ float bf2f(short s) {
  uint32_t u = ((uint32_t)(uint16_t)s) << 16;
  return __builtin_bit_cast(float, u);
}
__device__ __forceinline__ unsigned char f2fp8(float v) {
  return (unsigned char)(__builtin_amdgcn_cvt_pk_fp8_f32(v, 0.f, 0, false) & 0xFF);
}
__device__ __forceinline__ int pk4fp8(float a, float b, float c, float d) {
  int r = __builtin_amdgcn_cvt_pk_fp8_f32(a, b, 0, false);
  r = __builtin_amdgcn_cvt_pk_fp8_f32(c, d, r, true);
  return r;
}

// async 16B/lane global->LDS DMA (per-lane gptr; wave-uniform LDS base,
// HW scatters lane i -> base + 16*i)
__device__ __forceinline__ void glds16(const void* g, void* l) {
  __builtin_amdgcn_global_load_lds(
      (const __attribute__((address_space(1))) void*)g,
      (__attribute__((address_space(3))) void*)l, 16, 0, 0);
}
__device__ __forceinline__ void waitvm(int n) {
  if (n <= 0)      asm volatile("s_waitcnt vmcnt(0)" ::: "memory");
  else if (n == 2) asm volatile("s_waitcnt vmcnt(2)" ::: "memory");
  else if (n == 4) asm volatile("s_waitcnt vmcnt(4)" ::: "memory");
  else             asm volatile("s_waitcnt vmcnt(6)" ::: "memory");
}

// ---------------- merged prep kernel ----------------
// Grid 4609:
//   [0,256)    Cbp via LDS staging (both sections per block)
//   [256,512)  WXbp
//   [512,2560) E0f8p
//   [2560,4608) E0Tf8p
//   4608       zero-tail
// bf16 packed layout (Cbp/WXbp): idx = ((tile*KC + kc)*2 + h)*256 + l31*8 + j
// fp8 DMA-block layout (E0f8p/E0Tf8p): per (tile, dkc, sec) 1KB block;
//   byte u*8+jj, u = t*64 + h*32 + l31 -> element (k = (2dkc+t)*16 + h*8 + jj)

__global__ void prep_all(const float* __restrict__ W, const float* __restrict__ WX,
                         const float* __restrict__ E0,
                         short* __restrict__ Cbp, short* __restrict__ WXbp,
                         unsigned char* __restrict__ E0f8p,
                         unsigned char* __restrict__ E0Tf8p,
                         float* __restrict__ out) {
  const int b = blockIdx.x;
  if (b < 256) {
    // Cbp: block = rt(3b)<<5 | kc(4b)<<1 | h; computes C0 and C1 for
    // rows rt*32+[0,32), cols kc*16+h*8+[0,8).  C = WX*W (complex).
    const int rt = b >> 5, kc = (b >> 1) & 15, h = b & 1;
    const int tid = threadIdx.x;
    const int j = tid & 7, l31 = tid >> 3;        // l31 in [0,32)
    const int col0 = kc * 16 + h * 8;
    __shared__ float lWX[2][32][132];             // +4 pad: conflict-free bcast
    __shared__ float lW[2][128][8];
    #pragma unroll
    for (int ch = 0; ch < 2; ch++) {
      #pragma unroll
      for (int r = 0; r < 4; r++) {
        const int v = r * 256 + tid;
        const int n4 = v & 31, row = v >> 5;
        *(float4*)&lWX[ch][row][n4 * 4] =
            *(const float4*)(WX + ch * 32768 + (rt * 32 + row) * 128 + n4 * 4);
      }
      const int n = tid >> 1, half = tid & 1;
      *(float4*)&lW[ch][n][half * 4] =
          *(const float4*)(W + ch * 32768 + n * 256 + col0 + half * 4);
    }
    __syncthreads();
    float c0 = 0.f, c1 = 0.f;
    for (int n = 0; n < 128; n++) {
      const float wx0 = lWX[0][l31][n], wx1 = lWX[1][l31][n];
      const float w0 = lW[0][n][j], w1 = lW[1][n][j];
      c0 += wx0 * w0 - wx1 * w1;
      c1 += wx0 * w1 + wx1 * w0;
    }
    const int idx = b * 256 + tid;
    Cbp[idx] = f2bf(c0);
    Cbp[65536 + idx] = f2bf(c1);
  } else if (b < 512) {
    // WXbp: sections [-WX0, -WX1] (32768 shorts each), rows k(256), cols n(128), KC=8
    const int idx = (b - 256) * 256 + threadIdx.x;
    const int sec = idx >> 15, r = idx & 32767;
    const int j = r & 7, l31 = (r >> 3) & 31, h = (r >> 8) & 1, kc = (r >> 9) & 7, rt = r >> 12;
    const int row = rt * 32 + l31, col = kc * 16 + h * 8 + j;
    WXbp[idx] = f2bf(-WX[sec * 32768 + row * 128 + col]);
  } else if (b < 2560) {
    // E0f8p: sections [16*E0_re, -16*E0_im], rows m(1024), cols k(256); 8 dkc/m-tile
    const int idx = (b - 512) * 256 + threadIdx.x;   // [0, 524288)
    const int sec = idx >> 18, r = idx & 262143;
    const int blk = r >> 10, within = r & 1023;
    const int mt = blk >> 3, dkc = blk & 7;
    const int u = within >> 3, jj = within & 7;
    const int t = u >> 6, h = (u >> 5) & 1, l31 = u & 31;
    const int m = mt * 32 + l31, k = (dkc * 2 + t) * 16 + h * 8 + jj;
    const float v = E0[sec * 262144 + m * 256 + k] * (sec ? -16.f : 16.f);
    E0f8p[idx] = f2fp8(v);
  } else if (b < 4608) {
    // E0Tf8p: sections [16*E0_re^T, -16*E0_im^T], rows k(256), cols m(1024);
    // blocks (rt, c, dkc16)
    const int idx = (b - 2560) * 256 + threadIdx.x;   // [0, 524288)
    const int sec = idx >> 18, r = idx & 262143;
    const int blk = r >> 10, within = r & 1023;
    const int rt = blk >> 5, rem = blk & 31;
    const int c = rem >> 4, dkc = rem & 15;
    const int u = within >> 3, jj = within & 7;
    const int t = u >> 6, h = (u >> 5) & 1, l31 = u & 31;
    const int krow = rt * 32 + l31;
    const int mcol = c * 512 + (dkc * 2 + t) * 16 + h * 8 + jj;
    const float v = E0[sec * 262144 + mcol * 256 + krow] * (sec ? -16.f : 16.f);
    E0Tf8p[idx] = f2fp8(v);
  } else {
    if (threadIdx.x < 3) out[4194304 + threadIdx.x] = 0.f;
  }
}

// ---------------- main fused kernel ----------------
// grid 256 (batch tile of 32), block 512 (8 waves; wave w = row-tile).
// LDS (padded rows, stride % 128B == 8B -> worst 2-way bank aliasing):
//   buf0 [2][32][260]s = 33280B : x bf16; first 16640B aliased as
//                                 zf8 [32][520B] fp8
//   buf1 [2][32][260]s = 33280B : gx bf16 (true scale, Phase D huber)
//   bufy [3][32][132]s = 25344B : y bf16 [y0|y1|-y1]  (pre-loop only;
//                                 aliased as ring3 inside the it-loop)
//   gxf8 [2][32][264B] = 16896B : gx/S fp8 (Phase B B-operand)
//   ring0..2 (3 x 16KB) + ring3=bufy : 4-slot per-wave DMA ring (2KB/wave)
// Total ~154.25KB -> 1 block/CU.

#define RING(s) (((s) & 3) == 0 ? ring0 : ((s) & 3) == 1 ? ring1 : \
                 ((s) & 3) == 2 ? ring2 : ring3)

__global__ __attribute__((amdgpu_flat_work_group_size(512, 512), amdgpu_waves_per_eu(2, 2)))
void ista_main(
    const float* __restrict__ y,
    const float* __restrict__ etas,
    const float* __restrict__ gammas,
    const short* __restrict__ Cbp,
    const short* __restrict__ WXbp,
    const unsigned char* __restrict__ E0f8p,
    const unsigned char* __restrict__ E0Tf8p,
    float* __restrict__ out) {
  __shared__ short buf0[16640];
  __shared__ short buf1[16640];
  __shared__ short bufy[12672];
  __shared__ unsigned char gxf8[16896];
  __shared__ unsigned char ring0[16384];
  __shared__ unsigned char ring1[16384];
  __shared__ unsigned char ring2[16384];
  unsigned char* zf8 = (unsigned char*)buf0;   // [32][520B] fp8, aliases x-ch0
  unsigned char* ring3 = (unsigned char*)bufy; // bufy dead inside it-loop

  const int tid = threadIdx.x;
  const int w = tid >> 6;          // wave 0..7 == row-tile
  const int lane = tid & 63;
  const int l31 = lane & 31;
  const int h = lane >> 5;         // half-wave
  const int b0 = blockIdx.x * 32;
  const int lq = l31 * 8;          // bf16 packed-fragment lane offset (shorts)
  const int lane16 = lane * 16;    // per-lane global DMA offset (bytes)
  const int wslot = w * 2048;      // per-wave ring slot base (bytes)

  // ---- stage y -> bufy: [0]=y_re, [1]=y_im, [2]=-y_im  (rows 132 shorts)
  {
    const int bt = tid >> 4, j = tid & 15;
    const float* yb = y + (size_t)(b0 + bt) * 256;
    #pragma unroll
    for (int rep = 0; rep < 2; rep++) {
      const int jj = j + rep * 16;
      const int ch = jj >> 4, n8 = (jj & 15) << 3;
      const float4 v0 = *(const float4*)(yb + ch * 128 + n8);
      const float4 v1 = *(const float4*)(yb + ch * 128 + n8 + 4);
      s8v pk;
      pk[0] = f2bf(v0.x); pk[1] = f2bf(v0.y); pk[2] = f2bf(v0.z); pk[3] = f2bf(v0.w);
      pk[4] = f2bf(v1.x); pk[5] = f2bf(v1.y); pk[6] = f2bf(v1.z); pk[7] = f2bf(v1.w);
      const int off = bt * 132 + n8;
      *(s8v*)(bufy + ch * 4224 + off) = pk;
      if (ch == 1) {
        s8v nk;
        #pragma unroll
        for (int e = 0; e < 8; e++) nk[e] = pk[e] ^ (short)0x8000;
        *(s8v*)(bufy + 8448 + off) = nk;
      }
    }
  }
  // ---- zero buf0 (x = 0), including pad columns
  {
    s8v z = {0, 0, 0, 0, 0, 0, 0, 0};
    for (int i = tid * 8; i < 16640; i += 4096) *(s8v*)(buf0 + i) = z;
  }
  __syncthreads();

  // ---- d~ hoist: d = (-WX)*y fragments, iteration-invariant (32 VGPRs)
  f16v d0, d1;
  #pragma unroll
  for (int r = 0; r < 16; r++) { d0[r] = 0.f; d1[r] = 0.f; }
  #pragma unroll
  for (int kc = 0; kc < 8; kc++) {
    const int pa = ((w * 8 + kc) * 2 + h) * 256 + lq;
    const s8v a0 = *(const s8v*)(WXbp + pa);
    const s8v a1 = *(const s8v*)(WXbp + 32768 + pa);
    const int yo = l31 * 132 + ((kc * 2 + h) << 3);
    const s8v by0 = *(const s8v*)(bufy + yo);
    const s8v by1 = *(const s8v*)(bufy + 4224 + yo);
    const s8v by1n = *(const s8v*)(bufy + 8448 + yo);
    d0 = MFMA(a0, by0, d0);
    d0 = MFMA(a1, by1n, d0);
    d1 = MFMA(a0, by1, d1);
    d1 = MFMA(a1, by0, d1);
  }

  float ls = 0.f, leq = 0.f, cntf = 0.f;
  float S = 1.f;                   // dynamic scale: gx/S, s/S stored fp8
  float s16_last = 0.0625f;
  f16v xm0, xm1;
  #pragma unroll
  for (int r = 0; r < 16; r++) { xm0[r] = 0.f; xm1[r] = 0.f; }

  #pragma unroll 1
  for (int it = 1; it <= 10; it++) {
    const float gam = gammas[it];
    const float eta = etas[it];
    const float invS = 1.f / S;
    const float s16 = S * 0.0625f;   // accumulator -> true scale (weights x16)
    s16_last = s16;

    // ======== Phase A (bf16): ac = C*x - d~ ; gx = x - gam*ac ========
    f16v ac0 = d0, ac1 = d1;         // init from hoisted -d~
    if (it > 1) {
      #pragma unroll
      for (int kc = 0; kc < 16; kc++) {    // + C * x   (x = 0 at it=1)
        const int pa = ((w * 16 + kc) * 2 + h) * 256 + lq;
        const s8v a0 = *(const s8v*)(Cbp + pa);
        const s8v a1 = *(const s8v*)(Cbp + 65536 + pa);
        s8v a1n;                           // -C1 via sign-bit XOR (bit-identical
        #pragma unroll                     // to f2bf(-c1); RNE is sign-symmetric)
        for (int e = 0; e < 8; e++) a1n[e] = a1[e] ^ (short)0x8000;
        const int xo = l31 * 260 + ((kc * 2 + h) << 3);
        const s8v bx0 = *(const s8v*)(buf0 + xo);
        const s8v bx1 = *(const s8v*)(buf0 + 8320 + xo);
        ac0 = MFMA(a0, bx0, ac0);
        ac0 = MFMA(a1n, bx1, ac0);
        ac1 = MFMA(a0, bx1, ac1);
        ac1 = MFMA(a1, bx0, ac1);
      }
    }
    // gx = x - gam*ac; write gx bf16 (true) -> buf1, gx*invS fp8 -> gxf8
    #pragma unroll
    for (int r1 = 0; r1 < 4; r1++) {
      const int k0 = w * 32 + 8 * r1 + 4 * h;
      const int idx = l31 * 260 + k0;
      const s4v xv0 = *(const s4v*)(buf0 + idx);
      const s4v xv1 = *(const s4v*)(buf0 + 8320 + idx);
      float g0[4], g1[4];
      s4v p0, p1;
      #pragma unroll
      for (int r0 = 0; r0 < 4; r0++) {
        g0[r0] = bf2f(xv0[r0]) - gam * ac0[r1 * 4 + r0];
        g1[r0] = bf2f(xv1[r0]) - gam * ac1[r1 * 4 + r0];
        p0[r0] = f2bf(g0[r0]);
        p1[r0] = f2bf(g1[r0]);
      }
      *(s4v*)(buf1 + idx) = p0;
      *(s4v*)(buf1 + 8320 + idx) = p1;
      const int ga = l31 * 264 + k0;
      *(int*)(gxf8 + ga) = pk4fp8(g0[0] * invS, g0[1] * invS, g0[2] * invS, g0[3] * invS);
      *(int*)(gxf8 + 8448 + ga) = pk4fp8(g1[0] * invS, g1[1] * invS, g1[2] * invS, g1[3] * invS);
    }
    __syncthreads();

    #pragma unroll
    for (int r = 0; r < 16; r++) { xm0[r] = 0.f; xm1[r] = 0.f; }

    #pragma unroll 1
    for (int c = 0; c < 2; c++) {
      // ---- Phase B (fp8): z = Re(E0 * gx); 2 m-tile passes, 4-slot DMA ring ----
      #pragma unroll 1
      for (int q = 0; q < 2; q++) {
        const int mt = c * 16 + q * 8 + w;
        const unsigned char* gb = E0f8p + (size_t)(mt * 8) * 1024 + lane16;
        f16v zq;
        #pragma unroll
        for (int r = 0; r < 16; r++) zq[r] = 0.f;

#define B_ISSUE(d) do { \
    unsigned char* _s = RING(d) + wslot; \
    glds16(gb + (d) * 1024, _s); \
    glds16(gb + 262144 + (d) * 1024, _s + 1024); \
  } while (0)

        B_ISSUE(0); B_ISSUE(1); B_ISSUE(2); B_ISSUE(3);
        #pragma unroll
        for (int dkc = 0; dkc < 8; dkc++) {
          waitvm(dkc <= 4 ? 6 : dkc == 5 ? 4 : dkc == 6 ? 2 : 0);
          const unsigned char* Sl = RING(dkc) + wslot;
          __builtin_amdgcn_s_setprio(1);
          #pragma unroll
          for (int t = 0; t < 2; t++) {
            const i64 are = *(const i64*)(Sl + t * 512 + h * 256 + l31 * 8);
            const i64 aim = *(const i64*)(Sl + 1024 + t * 512 + h * 256 + l31 * 8);
            const int kc = dkc * 2 + t;
            const int go = l31 * 264 + (kc << 4) + h * 8;
            const i64 bg0 = *(const i64*)(gxf8 + go);
            const i64 bg1 = *(const i64*)(gxf8 + 8448 + go);
            zq = MFMA8(are, bg0, zq);
            zq = MFMA8(aim, bg1, zq);
          }
          __builtin_amdgcn_s_setprio(0);
          if (dkc + 4 < 8) B_ISSUE(dkc + 4);
        }
#undef B_ISSUE

        // shrink + losses (branch-free); write s*invS fp8 -> zf8 [32][520B]
        const int mtl = q * 8 + w;
        #pragma unroll
        for (int r1 = 0; r1 < 4; r1++) {
          float sv[4];
          #pragma unroll
          for (int r0 = 0; r0 < 4; r0++) {
            const float v = zq[r1 * 4 + r0] * s16;   // true z
            const float av = fabsf(v) - eta;
            const float rs = fmaxf(av, 0.f);
            ls += rs;
            if (it == 10) cntf += (rs > 1e-3f) ? 1.f : 0.f;
            sv[r0] = copysignf(rs, v) * invS;
          }
          const int ml = mtl * 32 + 8 * r1 + 4 * h;
          const int za = l31 * 520 + ml;
          *(int*)(zf8 + za) = pk4fp8(sv[0], sv[1], sv[2], sv[3]);
        }
      }
      __syncthreads();

      // ---- Phase C (fp8): xm += [E0reT; -E0imT] * s, 4-slot DMA ring ----
      {
        const unsigned char* tb = E0Tf8p + (size_t)((w * 2 + c) * 16) * 1024 + lane16;
#define C_ISSUE(d) do { \
    unsigned char* _s = RING(d) + wslot; \
    glds16(tb + (d) * 1024, _s); \
    glds16(tb + 262144 + (d) * 1024, _s + 1024); \
  } while (0)

        C_ISSUE(0); C_ISSUE(1); C_ISSUE(2); C_ISSUE(3);
        #pragma unroll
        for (int dkc = 0; dkc < 16; dkc++) {
          waitvm(dkc <= 12 ? 6 : dkc == 13 ? 4 : dkc == 14 ? 2 : 0);
          const unsigned char* Sl = RING(dkc) + wslot;
          __builtin_amdgcn_s_setprio(1);
          #pragma unroll
          for (int t = 0; t < 2; t++) {
            const i64 a0 = *(const i64*)(Sl + t * 512 + h * 256 + l31 * 8);
            const i64 a1 = *(const i64*)(Sl + 1024 + t * 512 + h * 256 + l31 * 8);
            const int kc = dkc * 2 + t;
            const i64 bz = *(const i64*)(zf8 + l31 * 520 + (kc << 4) + h * 8);
            xm0 = MFMA8(a0, bz, xm0);
            xm1 = MFMA8(a1, bz, xm1);
          }
          __builtin_amdgcn_s_setprio(0);
          if (dkc + 4 < 16) C_ISSUE(dkc + 4);
        }
#undef C_ISSUE
      }
      __syncthreads();
    }

    // ======== Phase D: huber(gx, xm*s16); x = xm*s16 (bf16) -> buf0 ========
    #pragma unroll
    for (int r1 = 0; r1 < 4; r1++) {
      const int k0 = w * 32 + 8 * r1 + 4 * h;
      const int idx = l31 * 260 + k0;
      const s4v gv0 = *(const s4v*)(buf1 + idx);
      const s4v gv1 = *(const s4v*)(buf1 + 8320 + idx);
      s4v p0, p1;
      #pragma unroll
      for (int r0 = 0; r0 < 4; r0++) {
        const float x0 = xm0[r1 * 4 + r0] * s16, x1 = xm1[r1 * 4 + r0] * s16;
        const float d0v = bf2f(gv0[r0]) - x0;
        const float d1v = bf2f(gv1[r0]) - x1;
        const float a0 = fabsf(d0v), a1 = fabsf(d1v);
        leq += (a0 < 1.f) ? 0.5f * d0v * d0v : (a0 - 0.5f);
        leq += (a1 < 1.f) ? 0.5f * d1v * d1v : (a1 - 0.5f);
        p0[r0] = f2bf(x0);
        p1[r0] = f2bf(x1);
      }
      *(s4v*)(buf0 + idx) = p0;
      *(s4v*)(buf0 + 8320 + idx) = p1;
    }
    __syncthreads();
    S *= 8.f;   // x grows ~9.3x/iter; keep fp8-stored gx/s near O(1)
  }

  // ---- write x_T (2, 8192, 256) fp32 from final xm (true scale)
  {
    const size_t ob = (size_t)(b0 + l31) * 256;
    #pragma unroll
    for (int r1 = 0; r1 < 4; r1++) {
      const int k0 = w * 32 + 8 * r1 + 4 * h;
      float4 v0, v1;
      v0.x = xm0[r1 * 4 + 0] * s16_last; v0.y = xm0[r1 * 4 + 1] * s16_last;
      v0.z = xm0[r1 * 4 + 2] * s16_last; v0.w = xm0[r1 * 4 + 3] * s16_last;
      v1.x = xm1[r1 * 4 + 0] * s16_last; v1.y = xm1[r1 * 4 + 1] * s16_last;
      v1.z = xm1[r1 * 4 + 2] * s16_last; v1.w = xm1[r1 * 4 + 3] * s16_last;
      *(float4*)(out + ob + k0) = v0;
      *(float4*)(out + 2097152 + ob + k0) = v1;
    }
  }
  // ---- scalar reductions
  #pragma unroll
  for (int off = 32; off > 0; off >>= 1) {
    ls += __shfl_down(ls, off);
    leq += __shfl_down(leq, off);
    cntf += __shfl_down(cntf, off);
  }
  if (lane == 0) {
    atomicAdd(out + 4194304, ls * (1.f / 8192.f));
    atomicAdd(out + 4194305, leq * (1.f / (2.f * 256.f * 8192.f * 10.f)));
    atomicAdd(out + 4194306, cntf * (1.f / 8192.f));
  }
}

extern "C" void kernel_launch(void* const* d_in, const int* in_sizes, int n_in,
                              void* d_out, int out_size, void* d_ws, size_t ws_size,
                              hipStream_t stream) {
  (void)in_sizes; (void)n_in; (void)out_size; (void)ws_size;
  const float* y = (const float*)d_in[0];
  const float* W = (const float*)d_in[1];
  const float* WX = (const float*)d_in[2];
  const float* E0 = (const float*)d_in[3];
  const float* etas = (const float*)d_in[4];
  const float* gammas = (const float*)d_in[5];
  float* out = (float*)d_out;

  short* Cbp = (short*)d_ws;                       // 2 * 65536 shorts used
  short* WXbp = Cbp + 196608;                      // 2 * 32768 shorts
  unsigned char* E0f8p = (unsigned char*)(WXbp + 65536);   // 524288 B
  unsigned char* E0Tf8p = E0f8p + 524288;                  // 524288 B (~1.6 MB total)

  prep_all<<<4609, 256, 0, stream>>>(W, WX, E0, Cbp, WXbp, E0f8p, E0Tf8p, out);
  ista_main<<<256, 512, 0, stream>>>(y, etas, gammas, Cbp, WXbp, E0f8p, E0Tf8p, out);
}

// Round 14
// 370.880 us; speedup vs baseline: 1.4697x; 1.0043x over previous
//
#include <hip/hip_runtime.h>
#include <stdint.h>

// ISTA_Net fused MFMA implementation for gfx950.  Round 22:
// ista_main VERBATIM from R21 (330.9us steady; 4-slot ring neutral, kept).
// This round: prep_all E0Tf8p branch was a 1KB-stride gather (4B used per
// 64B line -> 16x overfetch, latency-bound).  Rewritten as tiled transpose:
// 256 blocks stage 32x32x2sec E0 tiles via coalesced float4 row reads into
// LDS, then emit the byte-packed transposed layout as coalesced 4B stores.
// Output mapping verified element-wise identical to the old branch.
// Grid 4609 -> 2817.
// Shapes: M=1024, N=128, K=256, T=10, BATCH=8192. LAMBD=1.
// Outputs: x_T(2,8192,256) ++ loss_sparse ++ loss_eq/T ++ out_sparse

typedef short s8v __attribute__((ext_vector_type(8)));   // 8 bf16 MFMA operand
typedef short s4v __attribute__((ext_vector_type(4)));
typedef float f16v __attribute__((ext_vector_type(16))); // 32x32 MFMA accumulator
typedef long long i64;

#define MFMA(a, b, c)  __builtin_amdgcn_mfma_f32_32x32x16_bf16((a), (b), (c), 0, 0, 0)
#define MFMA8(a, b, c) __builtin_amdgcn_mfma_f32_32x32x16_fp8_fp8((a), (b), (c), 0, 0, 0)

__device__ __forceinline__ short f2bf(float f) {
  uint32_t u = __builtin_bit_cast(uint32_t, f);
  u = (u + 0x7FFFu + ((u >> 16) & 1u)) >> 16;   // RNE
  return (short)u;
}
__device__ __forceinline__ float bf2f(short s) {
  uint32_t u = ((uint32_t)(uint16_t)s) << 16;
  return __builtin_bit_cast(float, u);
}
__device__ __forceinline__ unsigned char f2fp8(float v) {
  return (unsigned char)(__builtin_amdgcn_cvt_pk_fp8_f32(v, 0.f, 0, false) & 0xFF);
}
__device__ __forceinline__ int pk4fp8(float a, float b, float c, float d) {
  int r = __builtin_amdgcn_cvt_pk_fp8_f32(a, b, 0, false);
  r = __builtin_amdgcn_cvt_pk_fp8_f32(c, d, r, true);
  return r;
}

// async 16B/lane global->LDS DMA (per-lane gptr; wave-uniform LDS base,
// HW scatters lane i -> base + 16*i)
__device__ __forceinline__ void glds16(const void* g, void* l) {
  __builtin_amdgcn_global_load_lds(
      (const __attribute__((address_space(1))) void*)g,
      (__attribute__((address_space(3))) void*)l, 16, 0, 0);
}
__device__ __forceinline__ void waitvm(int n) {
  if (n <= 0)      asm volatile("s_waitcnt vmcnt(0)" ::: "memory");
  else if (n == 2) asm volatile("s_waitcnt vmcnt(2)" ::: "memory");
  else if (n == 4) asm volatile("s_waitcnt vmcnt(4)" ::: "memory");
  else             asm volatile("s_waitcnt vmcnt(6)" ::: "memory");
}

// ---------------- merged prep kernel ----------------
// Grid 2817:
//   [0,256)     Cbp via LDS staging (both sections per block)
//   [256,512)   WXbp
//   [512,2560)  E0f8p
//   [2560,2816) E0Tf8p via tiled 32x32 LDS transpose (both secs per block)
//   2816        zero-tail
// bf16 packed layout (Cbp/WXbp): idx = ((tile*KC + kc)*2 + h)*256 + l31*8 + j
// fp8 DMA-block layout (E0f8p/E0Tf8p): per (tile, dkc, sec) 1KB block;
//   byte u*8+jj, u = t*64 + h*32 + l31 -> element (k = (2dkc+t)*16 + h*8 + jj)

__global__ void prep_all(const float* __restrict__ W, const float* __restrict__ WX,
                         const float* __restrict__ E0,
                         short* __restrict__ Cbp, short* __restrict__ WXbp,
                         unsigned char* __restrict__ E0f8p,
                         unsigned char* __restrict__ E0Tf8p,
                         float* __restrict__ out) {
  const int b = blockIdx.x;
  if (b < 256) {
    // Cbp: block = rt(3b)<<5 | kc(4b)<<1 | h; computes C0 and C1 for
    // rows rt*32+[0,32), cols kc*16+h*8+[0,8).  C = WX*W (complex).
    const int rt = b >> 5, kc = (b >> 1) & 15, h = b & 1;
    const int tid = threadIdx.x;
    const int j = tid & 7, l31 = tid >> 3;        // l31 in [0,32)
    const int col0 = kc * 16 + h * 8;
    __shared__ float lWX[2][32][132];             // +4 pad: conflict-free bcast
    __shared__ float lW[2][128][8];
    #pragma unroll
    for (int ch = 0; ch < 2; ch++) {
      #pragma unroll
      for (int r = 0; r < 4; r++) {
        const int v = r * 256 + tid;
        const int n4 = v & 31, row = v >> 5;
        *(float4*)&lWX[ch][row][n4 * 4] =
            *(const float4*)(WX + ch * 32768 + (rt * 32 + row) * 128 + n4 * 4);
      }
      const int n = tid >> 1, half = tid & 1;
      *(float4*)&lW[ch][n][half * 4] =
          *(const float4*)(W + ch * 32768 + n * 256 + col0 + half * 4);
    }
    __syncthreads();
    float c0 = 0.f, c1 = 0.f;
    for (int n = 0; n < 128; n++) {
      const float wx0 = lWX[0][l31][n], wx1 = lWX[1][l31][n];
      const float w0 = lW[0][n][j], w1 = lW[1][n][j];
      c0 += wx0 * w0 - wx1 * w1;
      c1 += wx0 * w1 + wx1 * w0;
    }
    const int idx = b * 256 + tid;
    Cbp[idx] = f2bf(c0);
    Cbp[65536 + idx] = f2bf(c1);
  } else if (b < 512) {
    // WXbp: sections [-WX0, -WX1] (32768 shorts each), rows k(256), cols n(128), KC=8
    const int idx = (b - 256) * 256 + threadIdx.x;
    const int sec = idx >> 15, r = idx & 32767;
    const int j = r & 7, l31 = (r >> 3) & 31, h = (r >> 8) & 1, kc = (r >> 9) & 7, rt = r >> 12;
    const int row = rt * 32 + l31, col = kc * 16 + h * 8 + j;
    WXbp[idx] = f2bf(-WX[sec * 32768 + row * 128 + col]);
  } else if (b < 2560) {
    // E0f8p: sections [16*E0_re, -16*E0_im], rows m(1024), cols k(256); 8 dkc/m-tile
    const int idx = (b - 512) * 256 + threadIdx.x;   // [0, 524288)
    const int sec = idx >> 18, r = idx & 262143;
    const int blk = r >> 10, within = r & 1023;
    const int mt = blk >> 3, dkc = blk & 7;
    const int u = within >> 3, jj = within & 7;
    const int t = u >> 6, h = (u >> 5) & 1, l31 = u & 31;
    const int m = mt * 32 + l31, k = (dkc * 2 + t) * 16 + h * 8 + jj;
    const float v = E0[sec * 262144 + m * 256 + k] * (sec ? -16.f : 16.f);
    E0f8p[idx] = f2fp8(v);
  } else if (b < 2816) {
    // E0Tf8p tiled: block nb = rt*32 + c*16 + dkc covers mcols
    // mcol0=c*512+dkc*32 +[0,32), krows rt*32+[0,32), both secs.
    // Stage: coalesced float4 row reads (row = one mcol, 32 krows = 128B).
    // Emit: byte pos p = u*8+jj -> element (mcl = t*16+h*8+jj, krl = l31);
    // thread writes 4 consecutive bytes (same u, jj0=(tid&1)*4) as one int.
    const int nb = b - 2560;
    const int rt = nb >> 5, c = (nb >> 4) & 1, dkc = nb & 15;
    const int mcol0 = c * 512 + dkc * 32, krow0 = rt * 32;
    const int tid = threadIdx.x;
    __shared__ float lT[2][32][36];   // [sec][mcol_local][krow_local], +4 pad
    #pragma unroll
    for (int sec = 0; sec < 2; sec++) {
      const int ml = tid >> 3, kq = tid & 7;
      *(float4*)&lT[sec][ml][kq * 4] =
          *(const float4*)(E0 + sec * 262144 + (mcol0 + ml) * 256 + krow0 + kq * 4);
    }
    __syncthreads();
    const int u = tid >> 1, jj0 = (tid & 1) * 4;
    const int t = u >> 6, h = (u >> 5) & 1, l31 = u & 31;
    const int mb = t * 16 + h * 8 + jj0;
    #pragma unroll
    for (int sec = 0; sec < 2; sec++) {
      const float sc = sec ? -16.f : 16.f;
      const int pk = pk4fp8(lT[sec][mb + 0][l31] * sc, lT[sec][mb + 1][l31] * sc,
                            lT[sec][mb + 2][l31] * sc, lT[sec][mb + 3][l31] * sc);
      *(int*)(E0Tf8p + sec * 262144 + nb * 1024 + tid * 4) = pk;
    }
  } else {
    if (threadIdx.x < 3) out[4194304 + threadIdx.x] = 0.f;
  }
}

// ---------------- main fused kernel ----------------
// grid 256 (batch tile of 32), block 512 (8 waves; wave w = row-tile).
// LDS (padded rows, stride % 128B == 8B -> worst 2-way bank aliasing):
//   buf0 [2][32][260]s = 33280B : x bf16; first 16640B aliased as
//                                 zf8 [32][520B] fp8
//   buf1 [2][32][260]s = 33280B : gx bf16 (true scale, Phase D huber)
//   bufy [3][32][132]s = 25344B : y bf16 [y0|y1|-y1]  (pre-loop only;
//                                 aliased as ring3 inside the it-loop)
//   gxf8 [2][32][264B] = 16896B : gx/S fp8 (Phase B B-operand)
//   ring0..2 (3 x 16KB) + ring3=bufy : 4-slot per-wave DMA ring (2KB/wave)
// Total ~154.25KB -> 1 block/CU.

#define RING(s) (((s) & 3) == 0 ? ring0 : ((s) & 3) == 1 ? ring1 : \
                 ((s) & 3) == 2 ? ring2 : ring3)

__global__ __attribute__((amdgpu_flat_work_group_size(512, 512), amdgpu_waves_per_eu(2, 2)))
void ista_main(
    const float* __restrict__ y,
    const float* __restrict__ etas,
    const float* __restrict__ gammas,
    const short* __restrict__ Cbp,
    const short* __restrict__ WXbp,
    const unsigned char* __restrict__ E0f8p,
    const unsigned char* __restrict__ E0Tf8p,
    float* __restrict__ out) {
  __shared__ short buf0[16640];
  __shared__ short buf1[16640];
  __shared__ short bufy[12672];
  __shared__ unsigned char gxf8[16896];
  __shared__ unsigned char ring0[16384];
  __shared__ unsigned char ring1[16384];
  __shared__ unsigned char ring2[16384];
  unsigned char* zf8 = (unsigned char*)buf0;   // [32][520B] fp8, aliases x-ch0
  unsigned char* ring3 = (unsigned char*)bufy; // bufy dead inside it-loop

  const int tid = threadIdx.x;
  const int w = tid >> 6;          // wave 0..7 == row-tile
  const int lane = tid & 63;
  const int l31 = lane & 31;
  const int h = lane >> 5;         // half-wave
  const int b0 = blockIdx.x * 32;
  const int lq = l31 * 8;          // bf16 packed-fragment lane offset (shorts)
  const int lane16 = lane * 16;    // per-lane global DMA offset (bytes)
  const int wslot = w * 2048;      // per-wave ring slot base (bytes)

  // ---- stage y -> bufy: [0]=y_re, [1]=y_im, [2]=-y_im  (rows 132 shorts)
  {
    const int bt = tid >> 4, j = tid & 15;
    const float* yb = y + (size_t)(b0 + bt) * 256;
    #pragma unroll
    for (int rep = 0; rep < 2; rep++) {
      const int jj = j + rep * 16;
      const int ch = jj >> 4, n8 = (jj & 15) << 3;
      const float4 v0 = *(const float4*)(yb + ch * 128 + n8);
      const float4 v1 = *(const float4*)(yb + ch * 128 + n8 + 4);
      s8v pk;
      pk[0] = f2bf(v0.x); pk[1] = f2bf(v0.y); pk[2] = f2bf(v0.z); pk[3] = f2bf(v0.w);
      pk[4] = f2bf(v1.x); pk[5] = f2bf(v1.y); pk[6] = f2bf(v1.z); pk[7] = f2bf(v1.w);
      const int off = bt * 132 + n8;
      *(s8v*)(bufy + ch * 4224 + off) = pk;
      if (ch == 1) {
        s8v nk;
        #pragma unroll
        for (int e = 0; e < 8; e++) nk[e] = pk[e] ^ (short)0x8000;
        *(s8v*)(bufy + 8448 + off) = nk;
      }
    }
  }
  // ---- zero buf0 (x = 0), including pad columns
  {
    s8v z = {0, 0, 0, 0, 0, 0, 0, 0};
    for (int i = tid * 8; i < 16640; i += 4096) *(s8v*)(buf0 + i) = z;
  }
  __syncthreads();

  // ---- d~ hoist: d = (-WX)*y fragments, iteration-invariant (32 VGPRs)
  f16v d0, d1;
  #pragma unroll
  for (int r = 0; r < 16; r++) { d0[r] = 0.f; d1[r] = 0.f; }
  #pragma unroll
  for (int kc = 0; kc < 8; kc++) {
    const int pa = ((w * 8 + kc) * 2 + h) * 256 + lq;
    const s8v a0 = *(const s8v*)(WXbp + pa);
    const s8v a1 = *(const s8v*)(WXbp + 32768 + pa);
    const int yo = l31 * 132 + ((kc * 2 + h) << 3);
    const s8v by0 = *(const s8v*)(bufy + yo);
    const s8v by1 = *(const s8v*)(bufy + 4224 + yo);
    const s8v by1n = *(const s8v*)(bufy + 8448 + yo);
    d0 = MFMA(a0, by0, d0);
    d0 = MFMA(a1, by1n, d0);
    d1 = MFMA(a0, by1, d1);
    d1 = MFMA(a1, by0, d1);
  }

  float ls = 0.f, leq = 0.f, cntf = 0.f;
  float S = 1.f;                   // dynamic scale: gx/S, s/S stored fp8
  float s16_last = 0.0625f;
  f16v xm0, xm1;
  #pragma unroll
  for (int r = 0; r < 16; r++) { xm0[r] = 0.f; xm1[r] = 0.f; }

  #pragma unroll 1
  for (int it = 1; it <= 10; it++) {
    const float gam = gammas[it];
    const float eta = etas[it];
    const float invS = 1.f / S;
    const float s16 = S * 0.0625f;   // accumulator -> true scale (weights x16)
    s16_last = s16;

    // ======== Phase A (bf16): ac = C*x - d~ ; gx = x - gam*ac ========
    f16v ac0 = d0, ac1 = d1;         // init from hoisted -d~
    if (it > 1) {
      #pragma unroll
      for (int kc = 0; kc < 16; kc++) {    // + C * x   (x = 0 at it=1)
        const int pa = ((w * 16 + kc) * 2 + h) * 256 + lq;
        const s8v a0 = *(const s8v*)(Cbp + pa);
        const s8v a1 = *(const s8v*)(Cbp + 65536 + pa);
        s8v a1n;                           // -C1 via sign-bit XOR (bit-identical
        #pragma unroll                     // to f2bf(-c1); RNE is sign-symmetric)
        for (int e = 0; e < 8; e++) a1n[e] = a1[e] ^ (short)0x8000;
        const int xo = l31 * 260 + ((kc * 2 + h) << 3);
        const s8v bx0 = *(const s8v*)(buf0 + xo);
        const s8v bx1 = *(const s8v*)(buf0 + 8320 + xo);
        ac0 = MFMA(a0, bx0, ac0);
        ac0 = MFMA(a1n, bx1, ac0);
        ac1 = MFMA(a0, bx1, ac1);
        ac1 = MFMA(a1, bx0, ac1);
      }
    }
    // gx = x - gam*ac; write gx bf16 (true) -> buf1, gx*invS fp8 -> gxf8
    #pragma unroll
    for (int r1 = 0; r1 < 4; r1++) {
      const int k0 = w * 32 + 8 * r1 + 4 * h;
      const int idx = l31 * 260 + k0;
      const s4v xv0 = *(const s4v*)(buf0 + idx);
      const s4v xv1 = *(const s4v*)(buf0 + 8320 + idx);
      float g0[4], g1[4];
      s4v p0, p1;
      #pragma unroll
      for (int r0 = 0; r0 < 4; r0++) {
        g0[r0] = bf2f(xv0[r0]) - gam * ac0[r1 * 4 + r0];
        g1[r0] = bf2f(xv1[r0]) - gam * ac1[r1 * 4 + r0];
        p0[r0] = f2bf(g0[r0]);
        p1[r0] = f2bf(g1[r0]);
      }
      *(s4v*)(buf1 + idx) = p0;
      *(s4v*)(buf1 + 8320 + idx) = p1;
      const int ga = l31 * 264 + k0;
      *(int*)(gxf8 + ga) = pk4fp8(g0[0] * invS, g0[1] * invS, g0[2] * invS, g0[3] * invS);
      *(int*)(gxf8 + 8448 + ga) = pk4fp8(g1[0] * invS, g1[1] * invS, g1[2] * invS, g1[3] * invS);
    }
    __syncthreads();

    #pragma unroll
    for (int r = 0; r < 16; r++) { xm0[r] = 0.f; xm1[r] = 0.f; }

    #pragma unroll 1
    for (int c = 0; c < 2; c++) {
      // ---- Phase B (fp8): z = Re(E0 * gx); 2 m-tile passes, 4-slot DMA ring ----
      #pragma unroll 1
      for (int q = 0; q < 2; q++) {
        const int mt = c * 16 + q * 8 + w;
        const unsigned char* gb = E0f8p + (size_t)(mt * 8) * 1024 + lane16;
        f16v zq;
        #pragma unroll
        for (int r = 0; r < 16; r++) zq[r] = 0.f;

#define B_ISSUE(d) do { \
    unsigned char* _s = RING(d) + wslot; \
    glds16(gb + (d) * 1024, _s); \
    glds16(gb + 262144 + (d) * 1024, _s + 1024); \
  } while (0)

        B_ISSUE(0); B_ISSUE(1); B_ISSUE(2); B_ISSUE(3);
        #pragma unroll
        for (int dkc = 0; dkc < 8; dkc++) {
          waitvm(dkc <= 4 ? 6 : dkc == 5 ? 4 : dkc == 6 ? 2 : 0);
          const unsigned char* Sl = RING(dkc) + wslot;
          __builtin_amdgcn_s_setprio(1);
          #pragma unroll
          for (int t = 0; t < 2; t++) {
            const i64 are = *(const i64*)(Sl + t * 512 + h * 256 + l31 * 8);
            const i64 aim = *(const i64*)(Sl + 1024 + t * 512 + h * 256 + l31 * 8);
            const int kc = dkc * 2 + t;
            const int go = l31 * 264 + (kc << 4) + h * 8;
            const i64 bg0 = *(const i64*)(gxf8 + go);
            const i64 bg1 = *(const i64*)(gxf8 + 8448 + go);
            zq = MFMA8(are, bg0, zq);
            zq = MFMA8(aim, bg1, zq);
          }
          __builtin_amdgcn_s_setprio(0);
          if (dkc + 4 < 8) B_ISSUE(dkc + 4);
        }
#undef B_ISSUE

        // shrink + losses (branch-free); write s*invS fp8 -> zf8 [32][520B]
        const int mtl = q * 8 + w;
        #pragma unroll
        for (int r1 = 0; r1 < 4; r1++) {
          float sv[4];
          #pragma unroll
          for (int r0 = 0; r0 < 4; r0++) {
            const float v = zq[r1 * 4 + r0] * s16;   // true z
            const float av = fabsf(v) - eta;
            const float rs = fmaxf(av, 0.f);
            ls += rs;
            if (it == 10) cntf += (rs > 1e-3f) ? 1.f : 0.f;
            sv[r0] = copysignf(rs, v) * invS;
          }
          const int ml = mtl * 32 + 8 * r1 + 4 * h;
          const int za = l31 * 520 + ml;
          *(int*)(zf8 + za) = pk4fp8(sv[0], sv[1], sv[2], sv[3]);
        }
      }
      __syncthreads();

      // ---- Phase C (fp8): xm += [E0reT; -E0imT] * s, 4-slot DMA ring ----
      {
        const unsigned char* tb = E0Tf8p + (size_t)((w * 2 + c) * 16) * 1024 + lane16;
#define C_ISSUE(d) do { \
    unsigned char* _s = RING(d) + wslot; \
    glds16(tb + (d) * 1024, _s); \
    glds16(tb + 262144 + (d) * 1024, _s + 1024); \
  } while (0)

        C_ISSUE(0); C_ISSUE(1); C_ISSUE(2); C_ISSUE(3);
        #pragma unroll
        for (int dkc = 0; dkc < 16; dkc++) {
          waitvm(dkc <= 12 ? 6 : dkc == 13 ? 4 : dkc == 14 ? 2 : 0);
          const unsigned char* Sl = RING(dkc) + wslot;
          __builtin_amdgcn_s_setprio(1);
          #pragma unroll
          for (int t = 0; t < 2; t++) {
            const i64 a0 = *(const i64*)(Sl + t * 512 + h * 256 + l31 * 8);
            const i64 a1 = *(const i64*)(Sl + 1024 + t * 512 + h * 256 + l31 * 8);
            const int kc = dkc * 2 + t;
            const i64 bz = *(const i64*)(zf8 + l31 * 520 + (kc << 4) + h * 8);
            xm0 = MFMA8(a0, bz, xm0);
            xm1 = MFMA8(a1, bz, xm1);
          }
          __builtin_amdgcn_s_setprio(0);
          if (dkc + 4 < 16) C_ISSUE(dkc + 4);
        }
#undef C_ISSUE
      }
      __syncthreads();
    }

    // ======== Phase D: huber(gx, xm*s16); x = xm*s16 (bf16) -> buf0 ========
    #pragma unroll
    for (int r1 = 0; r1 < 4; r1++) {
      const int k0 = w * 32 + 8 * r1 + 4 * h;
      const int idx = l31 * 260 + k0;
      const s4v gv0 = *(const s4v*)(buf1 + idx);
      const s4v gv1 = *(const s4v*)(buf1 + 8320 + idx);
      s4v p0, p1;
      #pragma unroll
      for (int r0 = 0; r0 < 4; r0++) {
        const float x0 = xm0[r1 * 4 + r0] * s16, x1 = xm1[r1 * 4 + r0] * s16;
        const float d0v = bf2f(gv0[r0]) - x0;
        const float d1v = bf2f(gv1[r0]) - x1;
        const float a0 = fabsf(d0v), a1 = fabsf(d1v);
        leq += (a0 < 1.f) ? 0.5f * d0v * d0v : (a0 - 0.5f);
        leq += (a1 < 1.f) ? 0.5f * d1v * d1v : (a1 - 0.5f);
        p0[r0] = f2bf(x0);
        p1[r0] = f2bf(x1);
      }
      *(s4v*)(buf0 + idx) = p0;
      *(s4v*)(buf0 + 8320 + idx) = p1;
    }
    __syncthreads();
    S *= 8.f;   // x grows ~9.3x/iter; keep fp8-stored gx/s near O(1)
  }

  // ---- write x_T (2, 8192, 256) fp32 from final xm (true scale)
  {
    const size_t ob = (size_t)(b0 + l31) * 256;
    #pragma unroll
    for (int r1 = 0; r1 < 4; r1++) {
      const int k0 = w * 32 + 8 * r1 + 4 * h;
      float4 v0, v1;
      v0.x = xm0[r1 * 4 + 0] * s16_last; v0.y = xm0[r1 * 4 + 1] * s16_last;
      v0.z = xm0[r1 * 4 + 2] * s16_last; v0.w = xm0[r1 * 4 + 3] * s16_last;
      v1.x = xm1[r1 * 4 + 0] * s16_last; v1.y = xm1[r1 * 4 + 1] * s16_last;
      v1.z = xm1[r1 * 4 + 2] * s16_last; v1.w = xm1[r1 * 4 + 3] * s16_last;
      *(float4*)(out + ob + k0) = v0;
      *(float4*)(out + 2097152 + ob + k0) = v1;
    }
  }
  // ---- scalar reductions
  #pragma unroll
  for (int off = 32; off > 0; off >>= 1) {
    ls += __shfl_down(ls, off);
    leq += __shfl_down(leq, off);
    cntf += __shfl_down(cntf, off);
  }
  if (lane == 0) {
    atomicAdd(out + 4194304, ls * (1.f / 8192.f));
    atomicAdd(out + 4194305, leq * (1.f / (2.f * 256.f * 8192.f * 10.f)));
    atomicAdd(out + 4194306, cntf * (1.f / 8192.f));
  }
}

extern "C" void kernel_launch(void* const* d_in, const int* in_sizes, int n_in,
                              void* d_out, int out_size, void* d_ws, size_t ws_size,
                              hipStream_t stream) {
  (void)in_sizes; (void)n_in; (void)out_size; (void)ws_size;
  const float* y = (const float*)d_in[0];
  const float* W = (const float*)d_in[1];
  const float* WX = (const float*)d_in[2];
  const float* E0 = (const float*)d_in[3];
  const float* etas = (const float*)d_in[4];
  const float* gammas = (const float*)d_in[5];
  float* out = (float*)d_out;

  short* Cbp = (short*)d_ws;                       // 2 * 65536 shorts used
  short* WXbp = Cbp + 196608;                      // 2 * 32768 shorts
  unsigned char* E0f8p = (unsigned char*)(WXbp + 65536);   // 524288 B
  unsigned char* E0Tf8p = E0f8p + 524288;                  // 524288 B (~1.6 MB total)

  prep_all<<<2817, 256, 0, stream>>>(W, WX, E0, Cbp, WXbp, E0f8p, E0Tf8p, out);
  ista_main<<<256, 512, 0, stream>>>(y, etas, gammas, Cbp, WXbp, E0f8p, E0Tf8p, out);
}